// Round 5
// baseline (269.714 us; speedup 1.0000x reference)
//
#include <hip/hip_runtime.h>

#define TPB 256
#define NW 4
#define NPTS 2000
#define M1C 100
#define M2C 5
#define KNN 20
#define CANDCAP 128   // knn scratch cap (knn1 cn<=~30 typ, knn2 cn<=100)

typedef float v2f __attribute__((ext_vector_type(2)));

// Bitwise-exact squared distance matching numpy fp32 sequential sum:
// ((dx*dx + dy*dy) + dz*dz), no FMA contraction.
__device__ __forceinline__ float dist3(float px, float py, float pz,
                                       float qx, float qy, float qz) {
#pragma clang fp contract(off)
    float dx = px - qx, dy = py - qy, dz = pz - qz;
    return dx * dx + dy * dy + dz * dz;
}

// Packed pair variant: identical per-component op order (sub,mul,add,add),
// so each component is bitwise identical to dist3.
__device__ __forceinline__ v2f dist3p(v2f px, v2f py, v2f pz, v2f q0, v2f q1, v2f q2) {
#pragma clang fp contract(off)
    v2f dx = px - q0, dy = py - q1, dz = pz - q2;
    v2f ax = dx * dx;
    v2f ay = dy * dy;
    v2f az = dz * dz;
    return (ax + ay) + az;
}

// Fused wave64 (value,index) argmax, min-index tie-break, DPP chain.
#define ARGMAX_STEP(ctrl, rm)                                                        \
    do {                                                                             \
        float ov = __int_as_float(__builtin_amdgcn_update_dpp(                       \
            (int)0xff800000, __float_as_int(v), ctrl, rm, 0xf, false));              \
        int oi = __builtin_amdgcn_update_dpp(0x7fffffff, i, ctrl, rm, 0xf, false);   \
        bool take = (ov > v) || (ov == v && oi < i);                                 \
        v = take ? ov : v;                                                           \
        i = take ? oi : i;                                                           \
    } while (0)

__device__ __forceinline__ void wave_argmax(float& v, int& i) {
    ARGMAX_STEP(0x111, 0xf);
    ARGMAX_STEP(0x112, 0xf);
    ARGMAX_STEP(0x114, 0xf);
    ARGMAX_STEP(0x118, 0xf);
    ARGMAX_STEP(0x142, 0xa);
    ARGMAX_STEP(0x143, 0xc);
    v = __int_as_float(__builtin_amdgcn_readlane(__float_as_int(v), 63));
    i = __builtin_amdgcn_readlane(i, 63);
}

#define FMAX_STEP(ctrl, rm)                                                          \
    do {                                                                             \
        float _t = __int_as_float(__builtin_amdgcn_update_dpp(                       \
            (int)0xff800000, __float_as_int(x), ctrl, rm, 0xf, false));              \
        x = fmaxf(x, _t);                                                            \
    } while (0)

__device__ __forceinline__ float wave_fmax(float x) {
    FMAX_STEP(0x111, 0xf);
    FMAX_STEP(0x112, 0xf);
    FMAX_STEP(0x114, 0xf);
    FMAX_STEP(0x118, 0xf);
    FMAX_STEP(0x142, 0xa);
    FMAX_STEP(0x143, 0xc);
    return __int_as_float(__builtin_amdgcn_readlane(__float_as_int(x), 63));
}

// ============ Fused kernel ============
// R16: cooperative barrier-synced FPS1, no atomics, no spin, no overlap.
// Post-mortems: R12 proved the 4-wave atomic/spin sync costs ~2000 cyc/iter
// (LDS RMW latency + release/acquire visibility + consumer-wave issue
// contention); R13-R15 proved a single-wave producer can't hold the cloud in
// VGPRs (compiler rematerializes from LDS, ~2750 cyc/iter). R16: TPB=256,
// 1 wave/SIMD, ALL 4 waves run FPS1 together (8 chunks each = the VGPR
// footprint R11 proved register-resident), one __syncthreads per iteration,
// double-buffered candidate slots, next-q from the in-register combine.
// knn1/MLP1 runs sequentially after FPS1 on all 4 waves (R12 lesson:
// overlap buys nothing when producer latency passes through 1:1).
__global__ __launch_bounds__(TPB, 1) void fused_kernel(
    const float* __restrict__ P,
    const float* __restrict__ W1, const float* __restrict__ b1,
    const float* __restrict__ W2, const float* __restrict__ b2,
    const float* __restrict__ W3, const float* __restrict__ b3,
    const float* __restrict__ D1, const float* __restrict__ bD1,
    const float* __restrict__ D2, const float* __restrict__ bD2,
    const float* __restrict__ D3, const float* __restrict__ bD3,
    float* __restrict__ out)
{
    __shared__ float sx[NPTS], sy[NPTS], sz[NPTS];
    __shared__ float smpx[M1C], smpy[M1C], smpz[M1C];
    __shared__ float s2x[M2C], s2y[M2C], s2z[M2C];
    __shared__ float f1s[M1C][5];
    __shared__ float knd[NW][CANDCAP];
    __shared__ int   kni[NW][CANDCAP];
    __shared__ float vin[M2C][KNN][8];     // knn2 valid-candidate inputs
    __shared__ __align__(16) float4 sA[2][4];
    __shared__ __align__(16) float  sZ[2][4];
    __shared__ float f2s[M2C][25];
    __shared__ float latent[45];
    __shared__ float decv[M2C][3];
    __shared__ float cfs[M2C][25];
    __shared__ float dec2s[M1C][3];
    __shared__ float cf2s[M1C][5];
    __shared__ float w2s[200], b2s[25], w3s[1260], b3s[45];

    const int b = blockIdx.x;
    const int tid = threadIdx.x;
    const int lane = tid & 63;
    const int wid = tid >> 6;

    const float R1SQ = (float)(0.3 * 0.3);   // f64 product then cast
    const float R2SQ = 1.0f;
    const float INVR1 = 1.0f / 0.3f;

    // ---- staging (all 4 waves) ----
    const float* Pb = P + (size_t)b * (NPTS * 3);
    for (int j = tid; j < NPTS; j += TPB) {
        sx[j] = Pb[3 * j + 0];
        sy[j] = Pb[3 * j + 1];
        sz[j] = Pb[3 * j + 2];
    }
    for (int t = tid; t < 200; t += TPB) w2s[t] = W2[t];
    for (int t = tid; t < 25; t += TPB) b2s[t] = b2[t];
    for (int t = tid; t < 1260; t += TPB) w3s[t] = W3[t];
    for (int t = tid; t < 45; t += TPB) b3s[t] = b3[t];
    __syncthreads();

    // ================= FPS1: cooperative, barrier-synced =================
    // Wave wid owns chunks [wid*8, wid*8+8); chunk k covers points
    // [k*64, k*64+64); j = k*64 + lane is the true linear point index.
    {
        v2f px2[4], py2[4], pz2[4], mind2[4];
#pragma unroll
        for (int p = 0; p < 4; ++p) {
#pragma unroll
            for (int h = 0; h < 2; ++h) {
                int k = (wid << 3) + 2 * p + h;
                int j = (k << 6) + lane;
                bool v = j < NPTS;
                int jc = v ? j : 0;
                px2[p][h] = v ? sx[jc] : 1e18f;
                py2[p][h] = v ? sy[jc] : 1e18f;
                pz2[p][h] = v ? sz[jc] : 1e18f;
                mind2[p][h] = v ? 1e10f : -1.0f;
            }
        }

        float qx = sx[0], qy = sy[0], qz = sz[0];
        for (int it = 0; it < M1C; ++it) {
            if (tid == 0) { smpx[it] = qx; smpy[it] = qy; smpz[it] = qz; }
            if (it == M1C - 1) break;   // last sample: no further argmax needed

            v2f q0 = {qx, qx}, q1 = {qy, qy}, q2 = {qz, qz};
            float m[8];
#pragma unroll
            for (int p = 0; p < 4; ++p) {
                v2f d = dist3p(px2[p], py2[p], pz2[p], q0, q1, q2);
                v2f mm;
                mm[0] = fminf(mind2[p][0], d[0]);
                mm[1] = fminf(mind2[p][1], d[1]);
                mind2[p] = mm;
                m[2 * p] = mm[0];
                m[2 * p + 1] = mm[1];
            }
            // tree argmax over the wave's 8 chunks; strict > keeps lowest
            // chunk on ties (local order == global order within the wave's
            // contiguous range)
            float va = m[0]; int ka = 0; if (m[1] > va) { va = m[1]; ka = 1; }
            float vb = m[2]; int kb = 2; if (m[3] > vb) { vb = m[3]; kb = 3; }
            float vc = m[4]; int kc = 4; if (m[5] > vc) { vc = m[5]; kc = 5; }
            float vd = m[6]; int kd = 6; if (m[7] > vd) { vd = m[7]; kd = 7; }
            if (vb > va) { va = vb; ka = kb; }
            if (vd > vc) { vc = vd; kc = kd; }
            if (vc > va) { va = vc; ka = kc; }
            float bv = va;
            int bi = (((wid << 3) + ka) << 6) | lane;   // global point index
            float lv = bv; int li = bi;
            wave_argmax(bv, bi);            // wave winner, min-index ties
            int p = it & 1;
            if (lv == bv && li == bi) {     // unique winner lane per wave
                float cx = px2[0][0], cy = py2[0][0], cz = pz2[0][0];
#pragma unroll
                for (int kk = 1; kk < 8; ++kk) {
                    bool t = (ka == kk);
                    cx = t ? px2[kk >> 1][kk & 1] : cx;
                    cy = t ? py2[kk >> 1][kk & 1] : cy;
                    cz = t ? pz2[kk >> 1][kk & 1] : cz;
                }
                sA[p][wid] = make_float4(bv, __int_as_float(bi), cx, cy);
                sZ[p][wid] = cz;
            }
            __syncthreads();   // winner slots visible to all 4 waves
            // (double-buffered sA/sZ: slot p is next overwritten at it+2,
            //  and iteration it+1's barrier separates that write from these
            //  reads -> single barrier per iteration is race-free)
            float4 a0 = sA[p][0], a1 = sA[p][1], a2 = sA[p][2], a3 = sA[p][3];
            float4 z0 = *(const float4*)&sZ[p][0];
            // tree combine in wid order, min-index ties
            float cv0 = a0.x; int ci0 = __float_as_int(a0.y);
            float x0 = a0.z, y0 = a0.w, zz0 = z0.x;
            {
                int ii = __float_as_int(a1.y);
                bool t = (a1.x > cv0) || (a1.x == cv0 && ii < ci0);
                if (t) { cv0 = a1.x; ci0 = ii; x0 = a1.z; y0 = a1.w; zz0 = z0.y; }
            }
            float cv1 = a2.x; int ci1 = __float_as_int(a2.y);
            float x1 = a2.z, y1 = a2.w, zz1 = z0.z;
            {
                int ii = __float_as_int(a3.y);
                bool t = (a3.x > cv1) || (a3.x == cv1 && ii < ci1);
                if (t) { cv1 = a3.x; ci1 = ii; x1 = a3.z; y1 = a3.w; zz1 = z0.w; }
            }
            bool t = (cv1 > cv0) || (cv1 == cv0 && ci1 < ci0);
            qx = t ? x1 : x0; qy = t ? y1 : y0; qz = t ? zz1 : zz0;
            // next q lives in registers -- no LDS broadcast read needed
        }
    }
    __syncthreads();   // smp[] fully published to all waves

    // ---- FPS2: 5 from 100 (wave 0 only; waves 1-3 start knn1 meanwhile) ----
    if (wid == 0) {
        float ax = smpx[lane], ay = smpy[lane], az = smpz[lane];
        bool vb2 = lane < (M1C - 64);
        float bx2 = vb2 ? smpx[lane + 64] : 1e18f;
        float by2 = vb2 ? smpy[lane + 64] : 1e18f;
        float bz2 = vb2 ? smpz[lane + 64] : 1e18f;
        float m2a = 1e10f;
        float m2b = vb2 ? 1e10f : -1.0f;
        int last2 = 0;
        for (int it = 0; it < M2C; ++it) {
            float fx = smpx[last2], fy = smpy[last2], fz = smpz[last2];
            if (lane == 0) { s2x[it] = fx; s2y[it] = fy; s2z[it] = fz; }
            m2a = fminf(m2a, dist3(ax, ay, az, fx, fy, fz));
            m2b = fminf(m2b, dist3(bx2, by2, bz2, fx, fy, fz));
            float v = m2a; int i = lane;
            if (m2b > v) { v = m2b; i = lane + 64; }
            wave_argmax(v, i);
            last2 = i;
        }
    }

    // ================= knn1 + MLP1: all 4 waves, sequential =================
    {
        float rw1[15], rb1[5];
#pragma unroll
        for (int i = 0; i < 15; ++i) rw1[i] = W1[i];
#pragma unroll
        for (int i = 0; i < 5; ++i) rb1[i] = b1[i];

        for (int s = wid; s < M1C; s += NW) {
            float qx = smpx[s], qy = smpy[s], qz = smpz[s];
            int cn = 0;
#pragma unroll 4
            for (int c = 0; c < 32; ++c) {
                int j = c * 64 + lane;
                float d = 0.0f; bool pred = false;
                if (j < NPTS) {
                    d = dist3(sx[j], sy[j], sz[j], qx, qy, qz);
                    pred = (d <= R1SQ);
                }
                unsigned long long mb = __ballot(pred);
                if (pred) {
                    int pos = cn + (int)__popcll(mb & ((1ull << lane) - 1ull));
                    if (pos < CANDCAP) { knd[wid][pos] = d; kni[wid][pos] = j; }
                }
                cn += (int)__popcll(mb);
            }
            if (cn > CANDCAP) cn = CANDCAP;  // P(Poisson λ≈14 > 128) ~ 1e-68
            float fmx[5];
#pragma unroll
            for (int f = 0; f < 5; ++f) fmx[f] = -1e30f;
            for (int t = lane; t < cn; t += 64) {
                float d = knd[wid][t]; int j = kni[wid][t];
                bool valid = true;
                if (cn > KNN) {
                    int rank = 0;
                    for (int u = 0; u < cn; ++u) {
                        float du = knd[wid][u]; int iu = kni[wid][u];
                        rank += (du < d || (du == d && iu < j)) ? 1 : 0;
                    }
                    valid = rank < KNN;   // replicates top_k stability (ties -> lower idx)
                }
                if (valid) {
                    float rx = (sx[j] - qx) * INVR1;
                    float ry = (sy[j] - qy) * INVR1;
                    float rz = (sz[j] - qz) * INVR1;
#pragma unroll
                    for (int f = 0; f < 5; ++f) {
                        float h = fmaf(rx, rw1[f], fmaf(ry, rw1[5 + f], fmaf(rz, rw1[10 + f], rb1[f])));
                        fmx[f] = fmaxf(fmx[f], fmaxf(h, 0.0f));
                    }
                }
            }
#pragma unroll
            for (int f = 0; f < 5; ++f) fmx[f] = wave_fmax(fmx[f]);
            if (lane == 0) {
#pragma unroll
                for (int f = 0; f < 5; ++f) f1s[s][f] = fmx[f];
            }
        }
    }
    __syncthreads();   // f1s + s2 ready

    // ================= tail: knn2 + MLP2 (DPP-free), MLP3, decoder =================
    for (int s = wid; s < M2C; s += NW) {
        float qx2 = s2x[s], qy2 = s2y[s], qz2 = s2z[s];
        int cn = 0;
#pragma unroll
        for (int c = 0; c < 2; ++c) {
            int j = c * 64 + lane;
            float d = 0.0f; bool pred = false;
            if (j < M1C) {
                d = dist3(smpx[j], smpy[j], smpz[j], qx2, qy2, qz2);
                pred = (d <= R2SQ);
            }
            unsigned long long mb = __ballot(pred);
            if (pred) {
                int pos = cn + (int)__popcll(mb & ((1ull << lane) - 1ull));
                knd[wid][pos] = d; kni[wid][pos] = j;   // cn<=100<CANDCAP
            }
            cn += (int)__popcll(mb);
        }
        // build valid-candidate input vectors (order-independent for max)
        int nv = 0;
#pragma unroll
        for (int c = 0; c < 2; ++c) {
            int t = c * 64 + lane;
            bool valid = false;
            float in8[8];
            if (t < cn) {
                float d = knd[wid][t]; int j = kni[wid][t];
                valid = true;
                if (cn > KNN) {
                    int rank = 0;
                    for (int u = 0; u < cn; ++u) {
                        float du = knd[wid][u]; int iu = kni[wid][u];
                        rank += (du < d || (du == d && iu < j)) ? 1 : 0;
                    }
                    valid = rank < KNN;
                }
                if (valid) {
                    in8[0] = smpx[j] - qx2; in8[1] = smpy[j] - qy2; in8[2] = smpz[j] - qz2;
#pragma unroll
                    for (int f = 0; f < 5; ++f) in8[3 + f] = f1s[j][f];
                }
            }
            unsigned long long mb = __ballot(valid);
            if (valid) {
                int pos = nv + (int)__popcll(mb & ((1ull << lane) - 1ull));
#pragma unroll
                for (int i = 0; i < 8; ++i) vin[s][pos][i] = in8[i];   // nv<=20
            }
            nv += (int)__popcll(mb);
        }
        // feature-per-lane max (no DPP chains); nv >= 1 (sample in own ball)
        if (lane < 25) {
            float hmx = -1e30f;
            for (int c = 0; c < nv; ++c) {
                float h = b2s[lane];
#pragma unroll
                for (int i = 0; i < 8; ++i) h = fmaf(vin[s][c][i], w2s[i * 25 + lane], h);
                hmx = fmaxf(hmx, fmaxf(h, 0.0f));
            }
            f2s[s][lane] = hmx;
        }
    }
    __syncthreads();

    // ---- MLP3 + max-pool -> latent (45) ----
    if (wid == 0 && lane < 45) {
        float lm = -1e30f;
        for (int r = 0; r < M2C; ++r) {
            float h = b3s[lane];
            h = fmaf(s2x[r] * 0.5f, w3s[0 * 45 + lane], h);
            h = fmaf(s2y[r] * 0.5f, w3s[1 * 45 + lane], h);
            h = fmaf(s2z[r] * 0.5f, w3s[2 * 45 + lane], h);
#pragma unroll
            for (int i = 0; i < 25; ++i) h = fmaf(f2s[r][i], w3s[(3 + i) * 45 + lane], h);
            lm = fmaxf(lm, fmaxf(h, 0.0f));
        }
        latent[lane] = lm;
    }
    __syncthreads();

    // ---- decoder stage 1: latent @ D1 + bD1 -> (5, 28) ----
    for (int t = tid; t < 140; t += TPB) {
        float acc = bD1[t];
        for (int i = 0; i < 45; i++) acc = fmaf(latent[i], D1[i * 140 + t], acc);
        int r = t / 28, c = t % 28;
        if (c < 3) decv[r][c] = acc;
        else cfs[r][c - 3] = fmaxf(acc, 0.0f);
    }
    __syncthreads();

    // ---- decoder stage 2: cf @ D2 + bD2 -> (100, 8) ----
    for (int t = tid; t < 800; t += TPB) {
        int r = t / 160, c = t % 160;
        float acc = bD2[c];
        for (int i = 0; i < 25; i++) acc = fmaf(cfs[r][i], D2[i * 160 + c], acc);
        int g = r * 20 + c / 8, c8 = c % 8;
        if (c8 < 3) dec2s[g][c8] = acc;
        else cf2s[g][c8 - 3] = fmaxf(acc, 0.0f);
    }
    __syncthreads();

    // ---- decoder stage 3 + compose output ----
    float* outb = out + (size_t)b * (NPTS * 3);
    for (int t = tid; t < NPTS * 3; t += TPB) {
        int n = t / 3, c = t % 3;
        int g = n / 20;
        int m = n / 400;
        int r60 = (n % 20) * 3 + c;
        float acc = bD3[r60];
        for (int i = 0; i < 5; i++) acc = fmaf(cf2s[g][i], D3[i * 60 + r60], acc);
        // out = ((dec*R3 + dec2)*R2 + dec3)*R1, R2 = 1
        float val = ((decv[m][c] * 2.0f + dec2s[g][c]) + acc) * 0.3f;
        outb[t] = val;
    }
}

extern "C" void kernel_launch(void* const* d_in, const int* in_sizes, int n_in,
                              void* d_out, int out_size, void* d_ws, size_t ws_size,
                              hipStream_t stream) {
    const float* P   = (const float*)d_in[0];
    const float* W1  = (const float*)d_in[1];
    const float* b1  = (const float*)d_in[2];
    const float* W2  = (const float*)d_in[3];
    const float* b2  = (const float*)d_in[4];
    const float* W3  = (const float*)d_in[5];
    const float* b3  = (const float*)d_in[6];
    const float* D1  = (const float*)d_in[7];
    const float* bD1 = (const float*)d_in[8];
    const float* D2  = (const float*)d_in[9];
    const float* bD2 = (const float*)d_in[10];
    const float* D3  = (const float*)d_in[11];
    const float* bD3 = (const float*)d_in[12];
    float* out = (float*)d_out;

    int B = in_sizes[0] / (NPTS * 3);
    hipLaunchKernelGGL(fused_kernel, dim3(B), dim3(TPB), 0, stream,
                       P, W1, b1, W2, b2, W3, b3, D1, bD1, D2, bD2, D3, bD3, out);
}

// Round 6
// 239.639 us; speedup vs baseline: 1.1255x; 1.1255x over previous
//
#include <hip/hip_runtime.h>

#define TPB 256
#define NW 4
#define NPTS 2000
#define M1C 100
#define M2C 5
#define KNN 20
#define CANDCAP 128   // knn scratch cap (knn1 cn<=~30 typ, knn2 cn<=100)
#define KSPLIT 95     // consumers do [0,95), producer does [95,100) after FPS

typedef float v2f __attribute__((ext_vector_type(2)));

// Bitwise-exact squared distance matching numpy fp32 sequential sum:
// ((dx*dx + dy*dy) + dz*dz), no FMA contraction.
__device__ __forceinline__ float dist3(float px, float py, float pz,
                                       float qx, float qy, float qz) {
#pragma clang fp contract(off)
    float dx = px - qx, dy = py - qy, dz = pz - qz;
    return dx * dx + dy * dy + dz * dz;
}

// Packed pair variant: identical per-component op order (sub,mul,add,add),
// so each component is bitwise identical to dist3.
__device__ __forceinline__ v2f dist3p(v2f px, v2f py, v2f pz, v2f q0, v2f q1, v2f q2) {
#pragma clang fp contract(off)
    v2f dx = px - q0, dy = py - q1, dz = pz - q2;
    v2f ax = dx * dx;
    v2f ay = dy * dy;
    v2f az = dz * dz;
    return (ax + ay) + az;
}

// Fused wave64 (value,index) argmax, min-index tie-break, DPP chain.
#define ARGMAX_STEP(ctrl, rm)                                                        \
    do {                                                                             \
        float ov = __int_as_float(__builtin_amdgcn_update_dpp(                       \
            (int)0xff800000, __float_as_int(v), ctrl, rm, 0xf, false));              \
        int oi = __builtin_amdgcn_update_dpp(0x7fffffff, i, ctrl, rm, 0xf, false);   \
        bool take = (ov > v) || (ov == v && oi < i);                                 \
        v = take ? ov : v;                                                           \
        i = take ? oi : i;                                                           \
    } while (0)

__device__ __forceinline__ void wave_argmax(float& v, int& i) {
    ARGMAX_STEP(0x111, 0xf);
    ARGMAX_STEP(0x112, 0xf);
    ARGMAX_STEP(0x114, 0xf);
    ARGMAX_STEP(0x118, 0xf);
    ARGMAX_STEP(0x142, 0xa);
    ARGMAX_STEP(0x143, 0xc);
    v = __int_as_float(__builtin_amdgcn_readlane(__float_as_int(v), 63));
    i = __builtin_amdgcn_readlane(i, 63);
}

#define FMAX_STEP(ctrl, rm)                                                          \
    do {                                                                             \
        float _t = __int_as_float(__builtin_amdgcn_update_dpp(                       \
            (int)0xff800000, __float_as_int(x), ctrl, rm, 0xf, false));              \
        x = fmaxf(x, _t);                                                            \
    } while (0)

__device__ __forceinline__ float wave_fmax(float x) {
    FMAX_STEP(0x111, 0xf);
    FMAX_STEP(0x112, 0xf);
    FMAX_STEP(0x114, 0xf);
    FMAX_STEP(0x118, 0xf);
    FMAX_STEP(0x142, 0xa);
    FMAX_STEP(0x143, 0xc);
    return __int_as_float(__builtin_amdgcn_readlane(__float_as_int(x), 63));
}

// X-macro over the 16 v2f chunk-pairs (32 chunks of 64 points).
#define PTS16(X) X(0) X(1) X(2) X(3) X(4) X(5) X(6) X(7) \
                 X(8) X(9) X(10) X(11) X(12) X(13) X(14) X(15)

// ============ Fused kernel ============
// R17 = R15 + FORCED register residency for the producer's point cloud.
// R13-R15 post-mortem: the compiler legally rematerializes ds_reads of the
// (read-only) staged cloud instead of keeping 128 VGPRs live; named SSA vars
// didn't stop it (VGPR_Count stayed 84). The forcing mechanism it cannot
// undo: an empty `asm volatile("" : "+v"(x))` on each point v2f INSIDE the
// FPS loop — the asm output is no longer the ds_read result, so remat is
// impossible and the value must live in a VGPR across the backedge.
// Also: points staged as float4 (1 b128 LDS read instead of 3 b32 in knn1
// scan + broadcast next-q), and the producer wave takes the last 5 knn1
// samples after FPS2 to balance the consumer waves (95/3 ~= 32 samples).
__global__ __launch_bounds__(TPB, 1) void fused_kernel(
    const float* __restrict__ P,
    const float* __restrict__ W1, const float* __restrict__ b1,
    const float* __restrict__ W2, const float* __restrict__ b2,
    const float* __restrict__ W3, const float* __restrict__ b3,
    const float* __restrict__ D1, const float* __restrict__ bD1,
    const float* __restrict__ D2, const float* __restrict__ bD2,
    const float* __restrict__ D3, const float* __restrict__ bD3,
    float* __restrict__ out)
{
    __shared__ __align__(16) float4 sp[NPTS];   // packed (x,y,z,0)
    __shared__ float smpx[M1C], smpy[M1C], smpz[M1C];
    __shared__ float s2x[M2C], s2y[M2C], s2z[M2C];
    __shared__ float f1s[M1C][5];
    __shared__ float knd[NW][CANDCAP];
    __shared__ int   kni[NW][CANDCAP];
    __shared__ float vin[M2C][KNN][8];     // knn2 valid-candidate inputs
    __shared__ int prog;                   // highest published FPS1 sample index
    __shared__ float f2s[M2C][25];
    __shared__ float latent[45];
    __shared__ float decv[M2C][3];
    __shared__ float cfs[M2C][25];
    __shared__ float dec2s[M1C][3];
    __shared__ float cf2s[M1C][5];
    __shared__ float w2s[200], b2s[25], w3s[1260], b3s[45];

    const int b = blockIdx.x;
    const int tid = threadIdx.x;
    const int lane = tid & 63;
    const int wid = tid >> 6;

    const float R1SQ = (float)(0.3 * 0.3);   // f64 product then cast
    const float R2SQ = 1.0f;
    const float INVR1 = 1.0f / 0.3f;

    // ---- staging (all 4 waves) ----
    const float* Pb = P + (size_t)b * (NPTS * 3);
    for (int j = tid; j < NPTS; j += TPB) {
        sp[j] = make_float4(Pb[3 * j + 0], Pb[3 * j + 1], Pb[3 * j + 2], 0.0f);
    }
    for (int t = tid; t < 200; t += TPB) w2s[t] = W2[t];
    for (int t = tid; t < 25; t += TPB) b2s[t] = b2[t];
    for (int t = tid; t < 1260; t += TPB) w3s[t] = W3[t];
    for (int t = tid; t < 45; t += TPB) b3s[t] = b3[t];
    if (tid == 0) prog = -1;
    __syncthreads();

    // shared knn1 body (scan uses float4 reads; math bit-identical)
#define KNN1_BODY(S, ROW) {                                                       \
        float qx = smpx[S], qy = smpy[S], qz = smpz[S];                           \
        int cn = 0;                                                               \
        _Pragma("unroll 4")                                                       \
        for (int c = 0; c < 32; ++c) {                                            \
            int j = c * 64 + lane;                                                \
            float d = 0.0f; bool pred = false;                                    \
            if (j < NPTS) {                                                       \
                float4 pj = sp[j];                                                \
                d = dist3(pj.x, pj.y, pj.z, qx, qy, qz);                          \
                pred = (d <= R1SQ);                                               \
            }                                                                     \
            unsigned long long mb = __ballot(pred);                               \
            if (pred) {                                                           \
                int pos = cn + (int)__popcll(mb & ((1ull << lane) - 1ull));       \
                if (pos < CANDCAP) { knd[ROW][pos] = d; kni[ROW][pos] = j; }      \
            }                                                                     \
            cn += (int)__popcll(mb);                                              \
        }                                                                         \
        if (cn > CANDCAP) cn = CANDCAP;                                           \
        float fmx[5];                                                             \
        _Pragma("unroll")                                                         \
        for (int f = 0; f < 5; ++f) fmx[f] = -1e30f;                              \
        for (int t = lane; t < cn; t += 64) {                                     \
            float d = knd[ROW][t]; int j = kni[ROW][t];                           \
            bool valid = true;                                                    \
            if (cn > KNN) {                                                       \
                int rank = 0;                                                     \
                for (int u = 0; u < cn; ++u) {                                    \
                    float du = knd[ROW][u]; int iu = kni[ROW][u];                 \
                    rank += (du < d || (du == d && iu < j)) ? 1 : 0;              \
                }                                                                 \
                valid = rank < KNN;                                               \
            }                                                                     \
            if (valid) {                                                          \
                float4 pj = sp[j];                                                \
                float rx = (pj.x - qx) * INVR1;                                   \
                float ry = (pj.y - qy) * INVR1;                                   \
                float rz = (pj.z - qz) * INVR1;                                   \
                _Pragma("unroll")                                                 \
                for (int f = 0; f < 5; ++f) {                                     \
                    float h = fmaf(rx, rw1[f],                                    \
                              fmaf(ry, rw1[5 + f],                               \
                              fmaf(rz, rw1[10 + f], rb1[f])));                    \
                    fmx[f] = fmaxf(fmx[f], fmaxf(h, 0.0f));                       \
                }                                                                 \
            }                                                                     \
        }                                                                         \
        _Pragma("unroll")                                                         \
        for (int f = 0; f < 5; ++f) fmx[f] = wave_fmax(fmx[f]);                   \
        if (lane == 0) {                                                          \
            _Pragma("unroll")                                                     \
            for (int f = 0; f < 5; ++f) f1s[S][f] = fmx[f];                       \
        }                                                                         \
    }

    if (wid == 0) {
        // ================= producer: single-wave FPS1, cloud in VGPRs ======
        // chunk k covers points [k*64, k*64+64); j = k*64 + lane.
#define DECLP(p) v2f px##p, py##p, pz##p, mind##p;
        PTS16(DECLP)
#undef DECLP

#define INITP(p) {                                                          \
        const int j0_ = (2*(p)) * 64 + lane;                                \
        const int j1_ = (2*(p)+1) * 64 + lane;                              \
        const bool v0_ = j0_ < NPTS, v1_ = j1_ < NPTS;                      \
        const float4 A_ = sp[v0_ ? j0_ : 0];                                \
        const float4 B_ = sp[v1_ ? j1_ : 0];                                \
        px##p[0] = v0_ ? A_.x : 1e18f;  px##p[1] = v1_ ? B_.x : 1e18f;      \
        py##p[0] = v0_ ? A_.y : 1e18f;  py##p[1] = v1_ ? B_.y : 1e18f;      \
        pz##p[0] = v0_ ? A_.z : 1e18f;  pz##p[1] = v1_ ? B_.z : 1e18f;      \
        mind##p[0] = v0_ ? 1e10f : -1.0f; mind##p[1] = v1_ ? 1e10f : -1.0f; \
    }
        PTS16(INITP)
#undef INITP

        float4 qq0 = sp[0];
        float qx = qq0.x, qy = qq0.y, qz = qq0.z;
        for (int it = 0; it < M1C; ++it) {
            if (lane == 0) {
                smpx[it] = qx; smpy[it] = qy; smpz[it] = qz;
                __hip_atomic_store(&prog, it, __ATOMIC_RELEASE,
                                   __HIP_MEMORY_SCOPE_WORKGROUP);
            }
            if (it == M1C - 1) break;   // last sample: no further argmax needed

            v2f q0 = {qx, qx}, q1 = {qy, qy}, q2 = {qz, qz};
            // 4 running-argmax streams (8 live regs). Stream s holds chunks
            // {c : c&3==s}; strict > keeps earliest chunk within a stream.
            float bv[4] = {-1e30f, -1e30f, -1e30f, -1e30f};
            int   bk[4] = {0, 0, 0, 0};
#define STEPP(p) {                                                          \
        v2f d = dist3p(px##p, py##p, pz##p, q0, q1, q2);                    \
        /* Forced liveness: asm redefines the point regs each iteration so  \
           the compiler cannot rematerialize them from LDS. */              \
        asm volatile("" : "+v"(px##p), "+v"(py##p), "+v"(pz##p));           \
        v2f mm;                                                             \
        mm[0] = fminf(mind##p[0], d[0]);                                    \
        mm[1] = fminf(mind##p[1], d[1]);                                    \
        mind##p = mm;                                                       \
        { const int c0 = 2*(p), s0 = c0 & 3;                                \
          bool t0 = mm[0] > bv[s0];                                         \
          bv[s0] = t0 ? mm[0] : bv[s0];                                     \
          bk[s0] = t0 ? c0 : bk[s0]; }                                      \
        { const int c1 = 2*(p)+1, s1 = c1 & 3;                              \
          bool t1 = mm[1] > bv[s1];                                         \
          bv[s1] = t1 ? mm[1] : bv[s1];                                     \
          bk[s1] = t1 ? c1 : bk[s1]; }                                      \
    }
            PTS16(STEPP)
#undef STEPP
            // cross-stream combine with (val, idx) min-index tie-break
            float V = bv[0]; int K = bk[0];
            {
                bool t = (bv[1] > V) || (bv[1] == V && bk[1] < K);
                V = t ? bv[1] : V; K = t ? bk[1] : K;
            }
            {
                bool t = (bv[2] > V) || (bv[2] == V && bk[2] < K);
                V = t ? bv[2] : V; K = t ? bk[2] : K;
            }
            {
                bool t = (bv[3] > V) || (bv[3] == V && bk[3] < K);
                V = t ? bv[3] : V; K = t ? bk[3] : K;
            }
            float bvv = V;
            int bi = (K << 6) | lane;       // = linear point index
            wave_argmax(bvv, bi);           // broadcast (value,index), min-idx ties
            float4 qq = sp[bi];             // uniform addr -> one b128 broadcast
            qx = qq.x; qy = qq.y; qz = qq.z;
        }

        // ---- FPS2: 5 from 100 (same wave, in-LDS smp) ----
        {
            float ax = smpx[lane], ay = smpy[lane], az = smpz[lane];
            bool vb2 = lane < (M1C - 64);
            float bx2 = vb2 ? smpx[lane + 64] : 1e18f;
            float by2 = vb2 ? smpy[lane + 64] : 1e18f;
            float bz2 = vb2 ? smpz[lane + 64] : 1e18f;
            float m2a = 1e10f;
            float m2b = vb2 ? 1e10f : -1.0f;
            int last2 = 0;
            for (int it = 0; it < M2C; ++it) {
                float fx = smpx[last2], fy = smpy[last2], fz = smpz[last2];
                if (lane == 0) { s2x[it] = fx; s2y[it] = fy; s2z[it] = fz; }
                m2a = fminf(m2a, dist3(ax, ay, az, fx, fy, fz));
                m2b = fminf(m2b, dist3(bx2, by2, bz2, fx, fy, fz));
                float v = m2a; int i = lane;
                if (m2b > v) { v = m2b; i = lane + 64; }
                wave_argmax(v, i);
                last2 = i;
            }
        }

        // ---- producer's knn1 tail share: samples [KSPLIT, 100) ----
        {
            float rw1[15], rb1[5];
#pragma unroll
            for (int i = 0; i < 15; ++i) rw1[i] = W1[i];
#pragma unroll
            for (int i = 0; i < 5; ++i) rb1[i] = b1[i];
            for (int s = KSPLIT; s < M1C; ++s) KNN1_BODY(s, 0);
        }
    } else {
        // ================= consumers: knn1 + MLP1 (waves 1-3) =================
        float rw1[15], rb1[5];
#pragma unroll
        for (int i = 0; i < 15; ++i) rw1[i] = W1[i];
#pragma unroll
        for (int i = 0; i < 5; ++i) rb1[i] = b1[i];

        for (int s = wid - 1; s < KSPLIT; s += (NW - 1)) {
            // wait until producer published sample s
            while (__hip_atomic_load(&prog, __ATOMIC_ACQUIRE,
                                     __HIP_MEMORY_SCOPE_WORKGROUP) < s)
                __builtin_amdgcn_s_sleep(1);
            KNN1_BODY(s, wid);
        }
    }
    __syncthreads();   // all 4 waves reach exactly once; f1s + s2 ready

    // ================= tail: knn2 + MLP2 (DPP-free), MLP3, decoder =================
    for (int s = wid; s < M2C; s += NW) {
        float qx2 = s2x[s], qy2 = s2y[s], qz2 = s2z[s];
        int cn = 0;
#pragma unroll
        for (int c = 0; c < 2; ++c) {
            int j = c * 64 + lane;
            float d = 0.0f; bool pred = false;
            if (j < M1C) {
                d = dist3(smpx[j], smpy[j], smpz[j], qx2, qy2, qz2);
                pred = (d <= R2SQ);
            }
            unsigned long long mb = __ballot(pred);
            if (pred) {
                int pos = cn + (int)__popcll(mb & ((1ull << lane) - 1ull));
                knd[wid][pos] = d; kni[wid][pos] = j;   // cn<=100<CANDCAP
            }
            cn += (int)__popcll(mb);
        }
        // build valid-candidate input vectors (order-independent for max)
        int nv = 0;
#pragma unroll
        for (int c = 0; c < 2; ++c) {
            int t = c * 64 + lane;
            bool valid = false;
            float in8[8];
            if (t < cn) {
                float d = knd[wid][t]; int j = kni[wid][t];
                valid = true;
                if (cn > KNN) {
                    int rank = 0;
                    for (int u = 0; u < cn; ++u) {
                        float du = knd[wid][u]; int iu = kni[wid][u];
                        rank += (du < d || (du == d && iu < j)) ? 1 : 0;
                    }
                    valid = rank < KNN;
                }
                if (valid) {
                    in8[0] = smpx[j] - qx2; in8[1] = smpy[j] - qy2; in8[2] = smpz[j] - qz2;
#pragma unroll
                    for (int f = 0; f < 5; ++f) in8[3 + f] = f1s[j][f];
                }
            }
            unsigned long long mb = __ballot(valid);
            if (valid) {
                int pos = nv + (int)__popcll(mb & ((1ull << lane) - 1ull));
#pragma unroll
                for (int i = 0; i < 8; ++i) vin[s][pos][i] = in8[i];   // nv<=20
            }
            nv += (int)__popcll(mb);
        }
        // feature-per-lane max (no DPP chains); nv >= 1 (sample in own ball)
        if (lane < 25) {
            float hmx = -1e30f;
            for (int c = 0; c < nv; ++c) {
                float h = b2s[lane];
#pragma unroll
                for (int i = 0; i < 8; ++i) h = fmaf(vin[s][c][i], w2s[i * 25 + lane], h);
                hmx = fmaxf(hmx, fmaxf(h, 0.0f));
            }
            f2s[s][lane] = hmx;
        }
    }
    __syncthreads();

    // ---- MLP3 + max-pool -> latent (45) ----
    if (wid == 0 && lane < 45) {
        float lm = -1e30f;
        for (int r = 0; r < M2C; ++r) {
            float h = b3s[lane];
            h = fmaf(s2x[r] * 0.5f, w3s[0 * 45 + lane], h);
            h = fmaf(s2y[r] * 0.5f, w3s[1 * 45 + lane], h);
            h = fmaf(s2z[r] * 0.5f, w3s[2 * 45 + lane], h);
#pragma unroll
            for (int i = 0; i < 25; ++i) h = fmaf(f2s[r][i], w3s[(3 + i) * 45 + lane], h);
            lm = fmaxf(lm, fmaxf(h, 0.0f));
        }
        latent[lane] = lm;
    }
    __syncthreads();

    // ---- decoder stage 1: latent @ D1 + bD1 -> (5, 28) ----
    for (int t = tid; t < 140; t += TPB) {
        float acc = bD1[t];
        for (int i = 0; i < 45; i++) acc = fmaf(latent[i], D1[i * 140 + t], acc);
        int r = t / 28, c = t % 28;
        if (c < 3) decv[r][c] = acc;
        else cfs[r][c - 3] = fmaxf(acc, 0.0f);
    }
    __syncthreads();

    // ---- decoder stage 2: cf @ D2 + bD2 -> (100, 8) ----
    for (int t = tid; t < 800; t += TPB) {
        int r = t / 160, c = t % 160;
        float acc = bD2[c];
        for (int i = 0; i < 25; i++) acc = fmaf(cfs[r][i], D2[i * 160 + c], acc);
        int g = r * 20 + c / 8, c8 = c % 8;
        if (c8 < 3) dec2s[g][c8] = acc;
        else cf2s[g][c8 - 3] = fmaxf(acc, 0.0f);
    }
    __syncthreads();

    // ---- decoder stage 3 + compose output ----
    float* outb = out + (size_t)b * (NPTS * 3);
    for (int t = tid; t < NPTS * 3; t += TPB) {
        int n = t / 3, c = t % 3;
        int g = n / 20;
        int m = n / 400;
        int r60 = (n % 20) * 3 + c;
        float acc = bD3[r60];
        for (int i = 0; i < 5; i++) acc = fmaf(cf2s[g][i], D3[i * 60 + r60], acc);
        // out = ((dec*R3 + dec2)*R2 + dec3)*R1, R2 = 1
        float val = ((decv[m][c] * 2.0f + dec2s[g][c]) + acc) * 0.3f;
        outb[t] = val;
    }
}

extern "C" void kernel_launch(void* const* d_in, const int* in_sizes, int n_in,
                              void* d_out, int out_size, void* d_ws, size_t ws_size,
                              hipStream_t stream) {
    const float* P   = (const float*)d_in[0];
    const float* W1  = (const float*)d_in[1];
    const float* b1  = (const float*)d_in[2];
    const float* W2  = (const float*)d_in[3];
    const float* b2  = (const float*)d_in[4];
    const float* W3  = (const float*)d_in[5];
    const float* b3  = (const float*)d_in[6];
    const float* D1  = (const float*)d_in[7];
    const float* bD1 = (const float*)d_in[8];
    const float* D2  = (const float*)d_in[9];
    const float* bD2 = (const float*)d_in[10];
    const float* D3  = (const float*)d_in[11];
    const float* bD3 = (const float*)d_in[12];
    float* out = (float*)d_out;

    int B = in_sizes[0] / (NPTS * 3);
    hipLaunchKernelGGL(fused_kernel, dim3(B), dim3(TPB), 0, stream,
                       P, W1, b1, W2, b2, W3, b3, D1, bD1, D2, bD2, D3, bD3, out);
}

// Round 7
// 186.954 us; speedup vs baseline: 1.4427x; 1.2818x over previous
//
#include <hip/hip_runtime.h>

#define TPB 512
#define NW 8
#define NPTS 2000
#define M1C 100
#define M2C 5
#define KNN 20
#define CANDCAP 128

typedef float v2f __attribute__((ext_vector_type(2)));

// Bitwise-exact squared distance matching numpy fp32 sequential sum:
// ((dx*dx + dy*dy) + dz*dz), no FMA contraction.
__device__ __forceinline__ float dist3(float px, float py, float pz,
                                       float qx, float qy, float qz) {
#pragma clang fp contract(off)
    float dx = px - qx, dy = py - qy, dz = pz - qz;
    return dx * dx + dy * dy + dz * dz;
}

// Packed pair variant: identical per-component op order (sub,mul,add,add),
// so each component is bitwise identical to dist3.
__device__ __forceinline__ v2f dist3p(v2f px, v2f py, v2f pz, v2f q0, v2f q1, v2f q2) {
#pragma clang fp contract(off)
    v2f dx = px - q0, dy = py - q1, dz = pz - q2;
    v2f ax = dx * dx;
    v2f ay = dy * dy;
    v2f az = dz * dz;
    return (ax + ay) + az;
}

// Fused wave64 (value,index) argmax, min-index tie-break, DPP chain.
#define ARGMAX_STEP(ctrl, rm)                                                        \
    do {                                                                             \
        float ov = __int_as_float(__builtin_amdgcn_update_dpp(                       \
            (int)0xff800000, __float_as_int(v), ctrl, rm, 0xf, false));              \
        int oi = __builtin_amdgcn_update_dpp(0x7fffffff, i, ctrl, rm, 0xf, false);   \
        bool take = (ov > v) || (ov == v && oi < i);                                 \
        v = take ? ov : v;                                                           \
        i = take ? oi : i;                                                           \
    } while (0)

__device__ __forceinline__ void wave_argmax(float& v, int& i) {
    ARGMAX_STEP(0x111, 0xf);
    ARGMAX_STEP(0x112, 0xf);
    ARGMAX_STEP(0x114, 0xf);
    ARGMAX_STEP(0x118, 0xf);
    ARGMAX_STEP(0x142, 0xa);
    ARGMAX_STEP(0x143, 0xc);
    v = __int_as_float(__builtin_amdgcn_readlane(__float_as_int(v), 63));
    i = __builtin_amdgcn_readlane(i, 63);
}

#define FMAX_STEP(ctrl, rm)                                                          \
    do {                                                                             \
        float _t = __int_as_float(__builtin_amdgcn_update_dpp(                       \
            (int)0xff800000, __float_as_int(x), ctrl, rm, 0xf, false));              \
        x = fmaxf(x, _t);                                                            \
    } while (0)

__device__ __forceinline__ float wave_fmax(float x) {
    FMAX_STEP(0x111, 0xf);
    FMAX_STEP(0x112, 0xf);
    FMAX_STEP(0x114, 0xf);
    FMAX_STEP(0x118, 0xf);
    FMAX_STEP(0x142, 0xa);
    FMAX_STEP(0x143, 0xc);
    return __int_as_float(__builtin_amdgcn_readlane(__float_as_int(x), 63));
}

// ============ Fused kernel ============
// R18 = R11 (best measured: 119us, 4-wave producer + overlapped consumers)
// with three surgical changes, arithmetic byte-identical:
//  1. s_setprio(1) on producer waves during FPS1 (T5's exact regime:
//     latency-critical producers vs throughput consumers on shared SIMDs).
//  2. Atomic counter -> per-wave release-stored sequence flags
//     (flg[parity][wave]=it+1): no LDS RMW, hot-spin relaxed polls + one
//     acquire fence. Consumers get a dedicated `prog` released by tid0 at
//     the TOP of each iteration (earlier than R11's mid-iteration post).
//     Safety = R11's two-slot + all-waves-gate argument, unchanged.
//  3. float4 sp[] staging (R17-verified bit-exact): consumers read 1 b128
//     per scanned point instead of 3 b32 -> less LDS/issue pressure
//     stealing producer slots.
__global__ __launch_bounds__(TPB, 2) void fused_kernel(
    const float* __restrict__ P,
    const float* __restrict__ W1, const float* __restrict__ b1,
    const float* __restrict__ W2, const float* __restrict__ b2,
    const float* __restrict__ W3, const float* __restrict__ b3,
    const float* __restrict__ D1, const float* __restrict__ bD1,
    const float* __restrict__ D2, const float* __restrict__ bD2,
    const float* __restrict__ D3, const float* __restrict__ bD3,
    float* __restrict__ out)
{
    __shared__ __align__(16) float4 sp[NPTS];   // packed (x,y,z,0)
    __shared__ float smpx[M1C], smpy[M1C], smpz[M1C];
    __shared__ float s2x[M2C], s2y[M2C], s2z[M2C];
    __shared__ float f1s[M1C][5];
    __shared__ float knd[NW][CANDCAP];
    __shared__ int   kni[NW][CANDCAP];
    __shared__ float vin[M2C][KNN][8];
    __shared__ __align__(16) float4 sA[2][4];
    __shared__ __align__(16) float  sZ[2][4];
    __shared__ int flg[2][4];              // per-wave sequence flags (it+1)
    __shared__ int prog;                   // highest published FPS1 sample
    __shared__ float f2s[M2C][25];
    __shared__ float latent[45];
    __shared__ float decv[M2C][3];
    __shared__ float cfs[M2C][25];
    __shared__ float dec2s[M1C][3];
    __shared__ float cf2s[M1C][5];
    __shared__ float w2s[200], b2s[25], w3s[1260], b3s[45];

    const int b = blockIdx.x;
    const int tid = threadIdx.x;
    const int lane = tid & 63;
    const int wid = tid >> 6;

    const float R1SQ = (float)(0.3 * 0.3);   // f64 product then cast
    const float R2SQ = 1.0f;
    const float INVR1 = 1.0f / 0.3f;

    // ---- staging (all 8 waves) ----
    const float* Pb = P + (size_t)b * (NPTS * 3);
    for (int j = tid; j < NPTS; j += TPB) {
        sp[j] = make_float4(Pb[3 * j + 0], Pb[3 * j + 1], Pb[3 * j + 2], 0.0f);
    }
    for (int t = tid; t < 200; t += TPB) w2s[t] = W2[t];
    for (int t = tid; t < 25; t += TPB) b2s[t] = b2[t];
    for (int t = tid; t < 1260; t += TPB) w3s[t] = W3[t];
    for (int t = tid; t < 45; t += TPB) b3s[t] = b3[t];
    if (tid < 8) ((int*)flg)[tid] = 0;
    if (tid == 0) prog = -1;
    __syncthreads();

    if (wid < 4) {
        // ================= producers: FPS1 (waves 0-3, tid 0..255) =================
        __builtin_amdgcn_s_setprio(1);
        v2f px2[4], py2[4], pz2[4], mind2[4];
#pragma unroll
        for (int p = 0; p < 4; ++p) {
#pragma unroll
            for (int h = 0; h < 2; ++h) {
                int k = 2 * p + h;
                int j = tid + (k << 8);
                bool v = j < NPTS;
                float4 A = sp[v ? j : 0];
                px2[p][h] = v ? A.x : 1e18f;
                py2[p][h] = v ? A.y : 1e18f;
                pz2[p][h] = v ? A.z : 1e18f;
                mind2[p][h] = v ? 1e10f : -1.0f;
            }
        }

        float4 qq0 = sp[0];
        float qx = qq0.x, qy = qq0.y, qz = qq0.z;
        for (int it = 0; it < M1C; ++it) {
            if (tid == 0) {
                smpx[it] = qx; smpy[it] = qy; smpz[it] = qz;
                __hip_atomic_store(&prog, it, __ATOMIC_RELEASE,
                                   __HIP_MEMORY_SCOPE_WORKGROUP);
            }
            if (it == M1C - 1) break;

            v2f q0 = {qx, qx}, q1 = {qy, qy}, q2 = {qz, qz};
            float m[8];
#pragma unroll
            for (int p = 0; p < 4; ++p) {
                v2f d = dist3p(px2[p], py2[p], pz2[p], q0, q1, q2);
                v2f mm;
                mm[0] = fminf(mind2[p][0], d[0]);
                mm[1] = fminf(mind2[p][1], d[1]);
                mind2[p] = mm;
                m[2 * p] = mm[0];
                m[2 * p + 1] = mm[1];
            }
            // tree argmax over 8 chunks; strict > keeps lowest chunk on ties
            float va = m[0]; int ka = 0; if (m[1] > va) { va = m[1]; ka = 1; }
            float vb = m[2]; int kb = 2; if (m[3] > vb) { vb = m[3]; kb = 3; }
            float vc = m[4]; int kc = 4; if (m[5] > vc) { vc = m[5]; kc = 5; }
            float vd = m[6]; int kd = 6; if (m[7] > vd) { vd = m[7]; kd = 7; }
            if (vb > va) { va = vb; ka = kb; }
            if (vd > vc) { vc = vd; kc = kd; }
            if (vc > va) { va = vc; ka = kc; }
            float bv = va; int bi = tid + (ka << 8);
            float lv = bv; int li = bi;
            wave_argmax(bv, bi);
            int p = it & 1;
            if (lv == bv && li == bi) {            // unique winner lane per wave
                int k = bi >> 8;
                float cx = px2[0][0], cy = py2[0][0], cz = pz2[0][0];
#pragma unroll
                for (int kk = 1; kk < 8; ++kk) {
                    bool t = (k == kk);
                    cx = t ? px2[kk >> 1][kk & 1] : cx;
                    cy = t ? py2[kk >> 1][kk & 1] : cy;
                    cz = t ? pz2[kk >> 1][kk & 1] : cz;
                }
                sA[p][wid] = make_float4(bv, __int_as_float(bi), cx, cy);
                sZ[p][wid] = cz;
            }
            if (lane == 0)
                __hip_atomic_store(&flg[p][wid], it + 1, __ATOMIC_RELEASE,
                                   __HIP_MEMORY_SCOPE_WORKGROUP);
            // hot spin until all 4 producer waves posted this iteration
            {
                const int need = it + 1;
                for (;;) {
                    int f0 = __hip_atomic_load(&flg[p][0], __ATOMIC_RELAXED,
                                               __HIP_MEMORY_SCOPE_WORKGROUP);
                    int f1 = __hip_atomic_load(&flg[p][1], __ATOMIC_RELAXED,
                                               __HIP_MEMORY_SCOPE_WORKGROUP);
                    int f2 = __hip_atomic_load(&flg[p][2], __ATOMIC_RELAXED,
                                               __HIP_MEMORY_SCOPE_WORKGROUP);
                    int f3 = __hip_atomic_load(&flg[p][3], __ATOMIC_RELAXED,
                                               __HIP_MEMORY_SCOPE_WORKGROUP);
                    if (f0 >= need && f1 >= need && f2 >= need && f3 >= need) break;
                }
                __builtin_amdgcn_fence(__ATOMIC_ACQUIRE, "workgroup");
            }
            float4 a0 = sA[p][0], a1 = sA[p][1], a2 = sA[p][2], a3 = sA[p][3];
            float4 z0 = *(const float4*)&sZ[p][0];
            // tree combine, min-index ties
            float cv0 = a0.x; int ci0 = __float_as_int(a0.y);
            float x0 = a0.z, y0 = a0.w, zz0 = z0.x;
            {
                int ii = __float_as_int(a1.y);
                bool t = (a1.x > cv0) || (a1.x == cv0 && ii < ci0);
                if (t) { cv0 = a1.x; ci0 = ii; x0 = a1.z; y0 = a1.w; zz0 = z0.y; }
            }
            float cv1 = a2.x; int ci1 = __float_as_int(a2.y);
            float x1 = a2.z, y1 = a2.w, zz1 = z0.z;
            {
                int ii = __float_as_int(a3.y);
                bool t = (a3.x > cv1) || (a3.x == cv1 && ii < ci1);
                if (t) { cv1 = a3.x; ci1 = ii; x1 = a3.z; y1 = a3.w; zz1 = z0.w; }
            }
            bool t = (cv1 > cv0) || (cv1 == cv0 && ci1 < ci0);
            qx = t ? x1 : x0; qy = t ? y1 : y0; qz = t ? zz1 : zz0;
        }

        if (wid == 0) {
            // ---- FPS2: 5 from 100 (single wave, in-LDS smp) ----
            float ax = smpx[lane], ay = smpy[lane], az = smpz[lane];
            bool vb2 = lane < (M1C - 64);
            float bx2 = vb2 ? smpx[lane + 64] : 1e18f;
            float by2 = vb2 ? smpy[lane + 64] : 1e18f;
            float bz2 = vb2 ? smpz[lane + 64] : 1e18f;
            float m2a = 1e10f;
            float m2b = vb2 ? 1e10f : -1.0f;
            int last2 = 0;
            for (int it = 0; it < M2C; ++it) {
                float fx = smpx[last2], fy = smpy[last2], fz = smpz[last2];
                if (lane == 0) { s2x[it] = fx; s2y[it] = fy; s2z[it] = fz; }
                m2a = fminf(m2a, dist3(ax, ay, az, fx, fy, fz));
                m2b = fminf(m2b, dist3(bx2, by2, bz2, fx, fy, fz));
                float v = m2a; int i = lane;
                if (m2b > v) { v = m2b; i = lane + 64; }
                wave_argmax(v, i);
                last2 = i;
            }
        }
        __builtin_amdgcn_s_setprio(0);
    } else {
        // ================= consumers: knn1 + MLP1 (waves 4-7) =================
        float rw1[15], rb1[5];
#pragma unroll
        for (int i = 0; i < 15; ++i) rw1[i] = W1[i];
#pragma unroll
        for (int i = 0; i < 5; ++i) rb1[i] = b1[i];

        for (int s = wid - 4; s < M1C; s += 4) {
            // wait until producer published sample s
            while (__hip_atomic_load(&prog, __ATOMIC_ACQUIRE,
                                     __HIP_MEMORY_SCOPE_WORKGROUP) < s)
                __builtin_amdgcn_s_sleep(1);
            float qx = smpx[s], qy = smpy[s], qz = smpz[s];
            int cn = 0;
#pragma unroll 4
            for (int c = 0; c < 32; ++c) {
                int j = c * 64 + lane;
                float d = 0.0f; bool pred = false;
                if (j < NPTS) {
                    float4 pj = sp[j];
                    d = dist3(pj.x, pj.y, pj.z, qx, qy, qz);
                    pred = (d <= R1SQ);
                }
                unsigned long long mb = __ballot(pred);
                if (pred) {
                    int pos = cn + (int)__popcll(mb & ((1ull << lane) - 1ull));
                    if (pos < CANDCAP) { knd[wid][pos] = d; kni[wid][pos] = j; }
                }
                cn += (int)__popcll(mb);
            }
            if (cn > CANDCAP) cn = CANDCAP;  // P(Poisson λ≈14 > 128) ~ 1e-68
            float fmx[5];
#pragma unroll
            for (int f = 0; f < 5; ++f) fmx[f] = -1e30f;
            for (int t = lane; t < cn; t += 64) {
                float d = knd[wid][t]; int j = kni[wid][t];
                bool valid = true;
                if (cn > KNN) {
                    int rank = 0;
                    for (int u = 0; u < cn; ++u) {
                        float du = knd[wid][u]; int iu = kni[wid][u];
                        rank += (du < d || (du == d && iu < j)) ? 1 : 0;
                    }
                    valid = rank < KNN;   // replicates top_k stability (ties -> lower idx)
                }
                if (valid) {
                    float4 pj = sp[j];
                    float rx = (pj.x - qx) * INVR1;
                    float ry = (pj.y - qy) * INVR1;
                    float rz = (pj.z - qz) * INVR1;
#pragma unroll
                    for (int f = 0; f < 5; ++f) {
                        float h = fmaf(rx, rw1[f], fmaf(ry, rw1[5 + f], fmaf(rz, rw1[10 + f], rb1[f])));
                        fmx[f] = fmaxf(fmx[f], fmaxf(h, 0.0f));
                    }
                }
            }
#pragma unroll
            for (int f = 0; f < 5; ++f) fmx[f] = wave_fmax(fmx[f]);
            if (lane == 0) {
#pragma unroll
                for (int f = 0; f < 5; ++f) f1s[s][f] = fmx[f];
            }
        }
    }
    __syncthreads();   // all 8 waves reach exactly once

    // ================= tail: knn2 + MLP2 (DPP-free), MLP3, decoder =================
    for (int s = wid; s < M2C; s += NW) {
        float qx2 = s2x[s], qy2 = s2y[s], qz2 = s2z[s];
        int cn = 0;
#pragma unroll
        for (int c = 0; c < 2; ++c) {
            int j = c * 64 + lane;
            float d = 0.0f; bool pred = false;
            if (j < M1C) {
                d = dist3(smpx[j], smpy[j], smpz[j], qx2, qy2, qz2);
                pred = (d <= R2SQ);
            }
            unsigned long long mb = __ballot(pred);
            if (pred) {
                int pos = cn + (int)__popcll(mb & ((1ull << lane) - 1ull));
                knd[wid][pos] = d; kni[wid][pos] = j;   // cn<=100<CANDCAP
            }
            cn += (int)__popcll(mb);
        }
        // build valid-candidate input vectors (order-independent for max)
        int nv = 0;
#pragma unroll
        for (int c = 0; c < 2; ++c) {
            int t = c * 64 + lane;
            bool valid = false;
            float in8[8];
            if (t < cn) {
                float d = knd[wid][t]; int j = kni[wid][t];
                valid = true;
                if (cn > KNN) {
                    int rank = 0;
                    for (int u = 0; u < cn; ++u) {
                        float du = knd[wid][u]; int iu = kni[wid][u];
                        rank += (du < d || (du == d && iu < j)) ? 1 : 0;
                    }
                    valid = rank < KNN;
                }
                if (valid) {
                    in8[0] = smpx[j] - qx2; in8[1] = smpy[j] - qy2; in8[2] = smpz[j] - qz2;
#pragma unroll
                    for (int f = 0; f < 5; ++f) in8[3 + f] = f1s[j][f];
                }
            }
            unsigned long long mb = __ballot(valid);
            if (valid) {
                int pos = nv + (int)__popcll(mb & ((1ull << lane) - 1ull));
#pragma unroll
                for (int i = 0; i < 8; ++i) vin[s][pos][i] = in8[i];   // nv<=20
            }
            nv += (int)__popcll(mb);
        }
        // feature-per-lane max (no DPP chains); nv >= 1 (sample in own ball)
        if (lane < 25) {
            float hmx = -1e30f;
            for (int c = 0; c < nv; ++c) {
                float h = b2s[lane];
#pragma unroll
                for (int i = 0; i < 8; ++i) h = fmaf(vin[s][c][i], w2s[i * 25 + lane], h);
                hmx = fmaxf(hmx, fmaxf(h, 0.0f));
            }
            f2s[s][lane] = hmx;
        }
    }
    __syncthreads();

    // ---- MLP3 + max-pool -> latent (45) ----
    if (wid == 0 && lane < 45) {
        float lm = -1e30f;
        for (int r = 0; r < M2C; ++r) {
            float h = b3s[lane];
            h = fmaf(s2x[r] * 0.5f, w3s[0 * 45 + lane], h);
            h = fmaf(s2y[r] * 0.5f, w3s[1 * 45 + lane], h);
            h = fmaf(s2z[r] * 0.5f, w3s[2 * 45 + lane], h);
#pragma unroll
            for (int i = 0; i < 25; ++i) h = fmaf(f2s[r][i], w3s[(3 + i) * 45 + lane], h);
            lm = fmaxf(lm, fmaxf(h, 0.0f));
        }
        latent[lane] = lm;
    }
    __syncthreads();

    // ---- decoder stage 1: latent @ D1 + bD1 -> (5, 28) ----
    for (int t = tid; t < 140; t += TPB) {
        float acc = bD1[t];
        for (int i = 0; i < 45; i++) acc = fmaf(latent[i], D1[i * 140 + t], acc);
        int r = t / 28, c = t % 28;
        if (c < 3) decv[r][c] = acc;
        else cfs[r][c - 3] = fmaxf(acc, 0.0f);
    }
    __syncthreads();

    // ---- decoder stage 2: cf @ D2 + bD2 -> (100, 8) ----
    for (int t = tid; t < 800; t += TPB) {
        int r = t / 160, c = t % 160;
        float acc = bD2[c];
        for (int i = 0; i < 25; i++) acc = fmaf(cfs[r][i], D2[i * 160 + c], acc);
        int g = r * 20 + c / 8, c8 = c % 8;
        if (c8 < 3) dec2s[g][c8] = acc;
        else cf2s[g][c8 - 3] = fmaxf(acc, 0.0f);
    }
    __syncthreads();

    // ---- decoder stage 3 + compose output ----
    float* outb = out + (size_t)b * (NPTS * 3);
    for (int t = tid; t < NPTS * 3; t += TPB) {
        int n = t / 3, c = t % 3;
        int g = n / 20;
        int m = n / 400;
        int r60 = (n % 20) * 3 + c;
        float acc = bD3[r60];
        for (int i = 0; i < 5; i++) acc = fmaf(cf2s[g][i], D3[i * 60 + r60], acc);
        // out = ((dec*R3 + dec2)*R2 + dec3)*R1, R2 = 1
        float val = ((decv[m][c] * 2.0f + dec2s[g][c]) + acc) * 0.3f;
        outb[t] = val;
    }
}

extern "C" void kernel_launch(void* const* d_in, const int* in_sizes, int n_in,
                              void* d_out, int out_size, void* d_ws, size_t ws_size,
                              hipStream_t stream) {
    const float* P   = (const float*)d_in[0];
    const float* W1  = (const float*)d_in[1];
    const float* b1  = (const float*)d_in[2];
    const float* W2  = (const float*)d_in[3];
    const float* b2  = (const float*)d_in[4];
    const float* W3  = (const float*)d_in[5];
    const float* b3  = (const float*)d_in[6];
    const float* D1  = (const float*)d_in[7];
    const float* bD1 = (const float*)d_in[8];
    const float* D2  = (const float*)d_in[9];
    const float* bD2 = (const float*)d_in[10];
    const float* D3  = (const float*)d_in[11];
    const float* bD3 = (const float*)d_in[12];
    float* out = (float*)d_out;

    int B = in_sizes[0] / (NPTS * 3);
    hipLaunchKernelGGL(fused_kernel, dim3(B), dim3(TPB), 0, stream,
                       P, W1, b1, W2, b2, W3, b3, D1, bD1, D2, bD2, D3, bD3, out);
}

// Round 9
// 186.204 us; speedup vs baseline: 1.4485x; 1.0040x over previous
//
#include <hip/hip_runtime.h>

#define TPB 512
#define NW 8
#define NPTS 2000
#define M1C 100
#define M2C 5
#define KNN 20
#define CANDCAP 128

typedef float v2f __attribute__((ext_vector_type(2)));

// Bitwise-exact squared distance matching numpy fp32 sequential sum:
// ((dx*dx + dy*dy) + dz*dz), no FMA contraction.
__device__ __forceinline__ float dist3(float px, float py, float pz,
                                       float qx, float qy, float qz) {
#pragma clang fp contract(off)
    float dx = px - qx, dy = py - qy, dz = pz - qz;
    return dx * dx + dy * dy + dz * dz;
}

// Packed pair variant: identical per-component op order (sub,mul,add,add),
// so each component is bitwise identical to dist3.
__device__ __forceinline__ v2f dist3p(v2f px, v2f py, v2f pz, v2f q0, v2f q1, v2f q2) {
#pragma clang fp contract(off)
    v2f dx = px - q0, dy = py - q1, dz = pz - q2;
    v2f ax = dx * dx;
    v2f ay = dy * dy;
    v2f az = dz * dz;
    return (ax + ay) + az;
}

// Fused wave64 (value,index) argmax, min-index tie-break, DPP chain.
// (kept for FPS2; FPS1 uses the cheaper split max+ballot below)
#define ARGMAX_STEP(ctrl, rm)                                                        \
    do {                                                                             \
        float ov = __int_as_float(__builtin_amdgcn_update_dpp(                       \
            (int)0xff800000, __float_as_int(v), ctrl, rm, 0xf, false));              \
        int oi = __builtin_amdgcn_update_dpp(0x7fffffff, i, ctrl, rm, 0xf, false);   \
        bool take = (ov > v) || (ov == v && oi < i);                                 \
        v = take ? ov : v;                                                           \
        i = take ? oi : i;                                                           \
    } while (0)

__device__ __forceinline__ void wave_argmax(float& v, int& i) {
    ARGMAX_STEP(0x111, 0xf);
    ARGMAX_STEP(0x112, 0xf);
    ARGMAX_STEP(0x114, 0xf);
    ARGMAX_STEP(0x118, 0xf);
    ARGMAX_STEP(0x142, 0xa);
    ARGMAX_STEP(0x143, 0xc);
    v = __int_as_float(__builtin_amdgcn_readlane(__float_as_int(v), 63));
    i = __builtin_amdgcn_readlane(i, 63);
}

#define FMAX_STEP(ctrl, rm)                                                          \
    do {                                                                             \
        float _t = __int_as_float(__builtin_amdgcn_update_dpp(                       \
            (int)0xff800000, __float_as_int(x), ctrl, rm, 0xf, false));              \
        x = fmaxf(x, _t);                                                            \
    } while (0)

__device__ __forceinline__ float wave_fmax(float x) {
    FMAX_STEP(0x111, 0xf);
    FMAX_STEP(0x112, 0xf);
    FMAX_STEP(0x114, 0xf);
    FMAX_STEP(0x118, 0xf);
    FMAX_STEP(0x142, 0xa);
    FMAX_STEP(0x143, 0xc);
    return __int_as_float(__builtin_amdgcn_readlane(__float_as_int(x), 63));
}

// int-min DPP chain (same lane pattern as FMAX, identity INT_MAX) — slow
// path of the split argmax, exact min-index over matched lanes.
#define IMIN_STEP(var, ctrl, rm)                                                     \
    do {                                                                             \
        int _t = __builtin_amdgcn_update_dpp(0x7fffffff, var, ctrl, rm, 0xf, false); \
        var = (_t < var) ? _t : var;                                                 \
    } while (0)

__device__ __forceinline__ int wave_imin(int c) {
    IMIN_STEP(c, 0x111, 0xf);
    IMIN_STEP(c, 0x112, 0xf);
    IMIN_STEP(c, 0x114, 0xf);
    IMIN_STEP(c, 0x118, 0xf);
    IMIN_STEP(c, 0x142, 0xa);
    IMIN_STEP(c, 0x143, 0xc);
    return __builtin_amdgcn_readlane(c, 63);
}

// ============ Fused kernel ============
// R20 = R19 resubmitted verbatim (R8 bench was an infra failure: container
// acquisition failed twice; kernel never ran). R19 = R18 (116.5us) with two
// surgical cuts on the FPS1 producer chain (R12's ablation proved consumer
// work hides fully; ~2400 cyc/iter is pure producer latency, fused (val,idx)
// DPP argmax ~330 cyc is its fattest term):
//  1. Split wave argmax: value-only DPP fmax chain (2 ops/step) + exact
//     index resolve via ballot(lv==gv). fmaxf returns an input bit-exactly
//     so the max lane always matches; single match (virtually always,
//     uniform branch) -> readlane(bi, ctz(mask)); ties -> masked int-min
//     DPP chain = jnp.argmax min-index semantics.
//  2. Poll the 4 arrival flags as 2 x ds_read_b64 instead of 4 x b32.
// All arithmetic byte-identical to R18.
__global__ __launch_bounds__(TPB, 2) void fused_kernel(
    const float* __restrict__ P,
    const float* __restrict__ W1, const float* __restrict__ b1,
    const float* __restrict__ W2, const float* __restrict__ b2,
    const float* __restrict__ W3, const float* __restrict__ b3,
    const float* __restrict__ D1, const float* __restrict__ bD1,
    const float* __restrict__ D2, const float* __restrict__ bD2,
    const float* __restrict__ D3, const float* __restrict__ bD3,
    float* __restrict__ out)
{
    __shared__ __align__(16) float4 sp[NPTS];   // packed (x,y,z,0)
    __shared__ float smpx[M1C], smpy[M1C], smpz[M1C];
    __shared__ float s2x[M2C], s2y[M2C], s2z[M2C];
    __shared__ float f1s[M1C][5];
    __shared__ float knd[NW][CANDCAP];
    __shared__ int   kni[NW][CANDCAP];
    __shared__ float vin[M2C][KNN][8];
    __shared__ __align__(16) float4 sA[2][4];
    __shared__ __align__(16) float  sZ[2][4];
    __shared__ __align__(16) int flg[2][4];   // per-wave sequence flags (it+1)
    __shared__ int prog;                      // highest published FPS1 sample
    __shared__ float f2s[M2C][25];
    __shared__ float latent[45];
    __shared__ float decv[M2C][3];
    __shared__ float cfs[M2C][25];
    __shared__ float dec2s[M1C][3];
    __shared__ float cf2s[M1C][5];
    __shared__ float w2s[200], b2s[25], w3s[1260], b3s[45];

    const int b = blockIdx.x;
    const int tid = threadIdx.x;
    const int lane = tid & 63;
    const int wid = tid >> 6;

    const float R1SQ = (float)(0.3 * 0.3);   // f64 product then cast
    const float R2SQ = 1.0f;
    const float INVR1 = 1.0f / 0.3f;

    // ---- staging (all 8 waves) ----
    const float* Pb = P + (size_t)b * (NPTS * 3);
    for (int j = tid; j < NPTS; j += TPB) {
        sp[j] = make_float4(Pb[3 * j + 0], Pb[3 * j + 1], Pb[3 * j + 2], 0.0f);
    }
    for (int t = tid; t < 200; t += TPB) w2s[t] = W2[t];
    for (int t = tid; t < 25; t += TPB) b2s[t] = b2[t];
    for (int t = tid; t < 1260; t += TPB) w3s[t] = W3[t];
    for (int t = tid; t < 45; t += TPB) b3s[t] = b3[t];
    if (tid < 8) ((int*)flg)[tid] = 0;
    if (tid == 0) prog = -1;
    __syncthreads();

    if (wid < 4) {
        // ================= producers: FPS1 (waves 0-3, tid 0..255) =================
        __builtin_amdgcn_s_setprio(1);
        v2f px2[4], py2[4], pz2[4], mind2[4];
#pragma unroll
        for (int p = 0; p < 4; ++p) {
#pragma unroll
            for (int h = 0; h < 2; ++h) {
                int k = 2 * p + h;
                int j = tid + (k << 8);
                bool v = j < NPTS;
                float4 A = sp[v ? j : 0];
                px2[p][h] = v ? A.x : 1e18f;
                py2[p][h] = v ? A.y : 1e18f;
                pz2[p][h] = v ? A.z : 1e18f;
                mind2[p][h] = v ? 1e10f : -1.0f;
            }
        }

        float4 qq0 = sp[0];
        float qx = qq0.x, qy = qq0.y, qz = qq0.z;
        for (int it = 0; it < M1C; ++it) {
            if (tid == 0) {
                smpx[it] = qx; smpy[it] = qy; smpz[it] = qz;
                __hip_atomic_store(&prog, it, __ATOMIC_RELEASE,
                                   __HIP_MEMORY_SCOPE_WORKGROUP);
            }
            if (it == M1C - 1) break;

            v2f q0 = {qx, qx}, q1 = {qy, qy}, q2 = {qz, qz};
            float m[8];
#pragma unroll
            for (int p = 0; p < 4; ++p) {
                v2f d = dist3p(px2[p], py2[p], pz2[p], q0, q1, q2);
                v2f mm;
                mm[0] = fminf(mind2[p][0], d[0]);
                mm[1] = fminf(mind2[p][1], d[1]);
                mind2[p] = mm;
                m[2 * p] = mm[0];
                m[2 * p + 1] = mm[1];
            }
            // tree argmax over 8 chunks; strict > keeps lowest chunk on ties
            float va = m[0]; int ka = 0; if (m[1] > va) { va = m[1]; ka = 1; }
            float vb = m[2]; int kb = 2; if (m[3] > vb) { vb = m[3]; kb = 3; }
            float vc = m[4]; int kc = 4; if (m[5] > vc) { vc = m[5]; kc = 5; }
            float vd = m[6]; int kd = 6; if (m[7] > vd) { vd = m[7]; kd = 7; }
            if (vb > va) { va = vb; ka = kb; }
            if (vd > vc) { vc = vd; kc = kd; }
            if (vc > va) { va = vc; ka = kc; }
            float lv = va;                      // lane-local best value
            int   li = tid + (ka << 8);         // lane-local best index
            // ---- split wave argmax: cheap value max + ballot index ----
            float gv = wave_fmax(lv);           // 2-op/step DPP chain
            unsigned long long mk = __ballot(lv == gv);   // >=1 lane matches
            int gbi;
            if (__popcll(mk) == 1) {            // uniform branch, ~always
                gbi = __builtin_amdgcn_readlane(li, (int)__builtin_ctzll(mk));
            } else {                            // exact min-index tie-break
                int c = (lv == gv) ? li : 0x7fffffff;
                gbi = wave_imin(c);
            }
            int p = it & 1;
            if (lv == gv && li == gbi) {        // unique winner lane per wave
                int k = gbi >> 8;
                float cx = px2[0][0], cy = py2[0][0], cz = pz2[0][0];
#pragma unroll
                for (int kk = 1; kk < 8; ++kk) {
                    bool t = (k == kk);
                    cx = t ? px2[kk >> 1][kk & 1] : cx;
                    cy = t ? py2[kk >> 1][kk & 1] : cy;
                    cz = t ? pz2[kk >> 1][kk & 1] : cz;
                }
                sA[p][wid] = make_float4(gv, __int_as_float(gbi), cx, cy);
                sZ[p][wid] = cz;
            }
            if (lane == 0)
                __hip_atomic_store(&flg[p][wid], it + 1, __ATOMIC_RELEASE,
                                   __HIP_MEMORY_SCOPE_WORKGROUP);
            // hot spin until all 4 producer waves posted this iteration
            {
                const int need = it + 1;
                for (;;) {
                    unsigned long long f01 = __hip_atomic_load(
                        (unsigned long long*)&flg[p][0], __ATOMIC_RELAXED,
                        __HIP_MEMORY_SCOPE_WORKGROUP);
                    unsigned long long f23 = __hip_atomic_load(
                        (unsigned long long*)&flg[p][2], __ATOMIC_RELAXED,
                        __HIP_MEMORY_SCOPE_WORKGROUP);
                    int f0 = (int)(f01 & 0xffffffffull);
                    int f1 = (int)(f01 >> 32);
                    int f2 = (int)(f23 & 0xffffffffull);
                    int f3 = (int)(f23 >> 32);
                    if (f0 >= need && f1 >= need && f2 >= need && f3 >= need) break;
                }
                __builtin_amdgcn_fence(__ATOMIC_ACQUIRE, "workgroup");
            }
            float4 a0 = sA[p][0], a1 = sA[p][1], a2 = sA[p][2], a3 = sA[p][3];
            float4 z0 = *(const float4*)&sZ[p][0];
            // tree combine, min-index ties
            float cv0 = a0.x; int ci0 = __float_as_int(a0.y);
            float x0 = a0.z, y0 = a0.w, zz0 = z0.x;
            {
                int ii = __float_as_int(a1.y);
                bool t = (a1.x > cv0) || (a1.x == cv0 && ii < ci0);
                if (t) { cv0 = a1.x; ci0 = ii; x0 = a1.z; y0 = a1.w; zz0 = z0.y; }
            }
            float cv1 = a2.x; int ci1 = __float_as_int(a2.y);
            float x1 = a2.z, y1 = a2.w, zz1 = z0.z;
            {
                int ii = __float_as_int(a3.y);
                bool t = (a3.x > cv1) || (a3.x == cv1 && ii < ci1);
                if (t) { cv1 = a3.x; ci1 = ii; x1 = a3.z; y1 = a3.w; zz1 = z0.w; }
            }
            bool t = (cv1 > cv0) || (cv1 == cv0 && ci1 < ci0);
            qx = t ? x1 : x0; qy = t ? y1 : y0; qz = t ? zz1 : zz0;
        }

        if (wid == 0) {
            // ---- FPS2: 5 from 100 (single wave, in-LDS smp) ----
            float ax = smpx[lane], ay = smpy[lane], az = smpz[lane];
            bool vb2 = lane < (M1C - 64);
            float bx2 = vb2 ? smpx[lane + 64] : 1e18f;
            float by2 = vb2 ? smpy[lane + 64] : 1e18f;
            float bz2 = vb2 ? smpz[lane + 64] : 1e18f;
            float m2a = 1e10f;
            float m2b = vb2 ? 1e10f : -1.0f;
            int last2 = 0;
            for (int it = 0; it < M2C; ++it) {
                float fx = smpx[last2], fy = smpy[last2], fz = smpz[last2];
                if (lane == 0) { s2x[it] = fx; s2y[it] = fy; s2z[it] = fz; }
                m2a = fminf(m2a, dist3(ax, ay, az, fx, fy, fz));
                m2b = fminf(m2b, dist3(bx2, by2, bz2, fx, fy, fz));
                float v = m2a; int i = lane;
                if (m2b > v) { v = m2b; i = lane + 64; }
                wave_argmax(v, i);
                last2 = i;
            }
        }
        __builtin_amdgcn_s_setprio(0);
    } else {
        // ================= consumers: knn1 + MLP1 (waves 4-7) =================
        float rw1[15], rb1[5];
#pragma unroll
        for (int i = 0; i < 15; ++i) rw1[i] = W1[i];
#pragma unroll
        for (int i = 0; i < 5; ++i) rb1[i] = b1[i];

        for (int s = wid - 4; s < M1C; s += 4) {
            // wait until producer published sample s
            while (__hip_atomic_load(&prog, __ATOMIC_ACQUIRE,
                                     __HIP_MEMORY_SCOPE_WORKGROUP) < s)
                __builtin_amdgcn_s_sleep(1);
            float qx = smpx[s], qy = smpy[s], qz = smpz[s];
            int cn = 0;
#pragma unroll 4
            for (int c = 0; c < 32; ++c) {
                int j = c * 64 + lane;
                float d = 0.0f; bool pred = false;
                if (j < NPTS) {
                    float4 pj = sp[j];
                    d = dist3(pj.x, pj.y, pj.z, qx, qy, qz);
                    pred = (d <= R1SQ);
                }
                unsigned long long mb = __ballot(pred);
                if (pred) {
                    int pos = cn + (int)__popcll(mb & ((1ull << lane) - 1ull));
                    if (pos < CANDCAP) { knd[wid][pos] = d; kni[wid][pos] = j; }
                }
                cn += (int)__popcll(mb);
            }
            if (cn > CANDCAP) cn = CANDCAP;  // P(Poisson λ≈14 > 128) ~ 1e-68
            float fmx[5];
#pragma unroll
            for (int f = 0; f < 5; ++f) fmx[f] = -1e30f;
            for (int t = lane; t < cn; t += 64) {
                float d = knd[wid][t]; int j = kni[wid][t];
                bool valid = true;
                if (cn > KNN) {
                    int rank = 0;
                    for (int u = 0; u < cn; ++u) {
                        float du = knd[wid][u]; int iu = kni[wid][u];
                        rank += (du < d || (du == d && iu < j)) ? 1 : 0;
                    }
                    valid = rank < KNN;   // replicates top_k stability (ties -> lower idx)
                }
                if (valid) {
                    float4 pj = sp[j];
                    float rx = (pj.x - qx) * INVR1;
                    float ry = (pj.y - qy) * INVR1;
                    float rz = (pj.z - qz) * INVR1;
#pragma unroll
                    for (int f = 0; f < 5; ++f) {
                        float h = fmaf(rx, rw1[f], fmaf(ry, rw1[5 + f], fmaf(rz, rw1[10 + f], rb1[f])));
                        fmx[f] = fmaxf(fmx[f], fmaxf(h, 0.0f));
                    }
                }
            }
#pragma unroll
            for (int f = 0; f < 5; ++f) fmx[f] = wave_fmax(fmx[f]);
            if (lane == 0) {
#pragma unroll
                for (int f = 0; f < 5; ++f) f1s[s][f] = fmx[f];
            }
        }
    }
    __syncthreads();   // all 8 waves reach exactly once

    // ================= tail: knn2 + MLP2 (DPP-free), MLP3, decoder =================
    for (int s = wid; s < M2C; s += NW) {
        float qx2 = s2x[s], qy2 = s2y[s], qz2 = s2z[s];
        int cn = 0;
#pragma unroll
        for (int c = 0; c < 2; ++c) {
            int j = c * 64 + lane;
            float d = 0.0f; bool pred = false;
            if (j < M1C) {
                d = dist3(smpx[j], smpy[j], smpz[j], qx2, qy2, qz2);
                pred = (d <= R2SQ);
            }
            unsigned long long mb = __ballot(pred);
            if (pred) {
                int pos = cn + (int)__popcll(mb & ((1ull << lane) - 1ull));
                knd[wid][pos] = d; kni[wid][pos] = j;   // cn<=100<CANDCAP
            }
            cn += (int)__popcll(mb);
        }
        // build valid-candidate input vectors (order-independent for max)
        int nv = 0;
#pragma unroll
        for (int c = 0; c < 2; ++c) {
            int t = c * 64 + lane;
            bool valid = false;
            float in8[8];
            if (t < cn) {
                float d = knd[wid][t]; int j = kni[wid][t];
                valid = true;
                if (cn > KNN) {
                    int rank = 0;
                    for (int u = 0; u < cn; ++u) {
                        float du = knd[wid][u]; int iu = kni[wid][u];
                        rank += (du < d || (du == d && iu < j)) ? 1 : 0;
                    }
                    valid = rank < KNN;
                }
                if (valid) {
                    in8[0] = smpx[j] - qx2; in8[1] = smpy[j] - qy2; in8[2] = smpz[j] - qz2;
#pragma unroll
                    for (int f = 0; f < 5; ++f) in8[3 + f] = f1s[j][f];
                }
            }
            unsigned long long mb = __ballot(valid);
            if (valid) {
                int pos = nv + (int)__popcll(mb & ((1ull << lane) - 1ull));
#pragma unroll
                for (int i = 0; i < 8; ++i) vin[s][pos][i] = in8[i];   // nv<=20
            }
            nv += (int)__popcll(mb);
        }
        // feature-per-lane max (no DPP chains); nv >= 1 (sample in own ball)
        if (lane < 25) {
            float hmx = -1e30f;
            for (int c = 0; c < nv; ++c) {
                float h = b2s[lane];
#pragma unroll
                for (int i = 0; i < 8; ++i) h = fmaf(vin[s][c][i], w2s[i * 25 + lane], h);
                hmx = fmaxf(hmx, fmaxf(h, 0.0f));
            }
            f2s[s][lane] = hmx;
        }
    }
    __syncthreads();

    // ---- MLP3 + max-pool -> latent (45) ----
    if (wid == 0 && lane < 45) {
        float lm = -1e30f;
        for (int r = 0; r < M2C; ++r) {
            float h = b3s[lane];
            h = fmaf(s2x[r] * 0.5f, w3s[0 * 45 + lane], h);
            h = fmaf(s2y[r] * 0.5f, w3s[1 * 45 + lane], h);
            h = fmaf(s2z[r] * 0.5f, w3s[2 * 45 + lane], h);
#pragma unroll
            for (int i = 0; i < 25; ++i) h = fmaf(f2s[r][i], w3s[(3 + i) * 45 + lane], h);
            lm = fmaxf(lm, fmaxf(h, 0.0f));
        }
        latent[lane] = lm;
    }
    __syncthreads();

    // ---- decoder stage 1: latent @ D1 + bD1 -> (5, 28) ----
    for (int t = tid; t < 140; t += TPB) {
        float acc = bD1[t];
        for (int i = 0; i < 45; i++) acc = fmaf(latent[i], D1[i * 140 + t], acc);
        int r = t / 28, c = t % 28;
        if (c < 3) decv[r][c] = acc;
        else cfs[r][c - 3] = fmaxf(acc, 0.0f);
    }
    __syncthreads();

    // ---- decoder stage 2: cf @ D2 + bD2 -> (100, 8) ----
    for (int t = tid; t < 800; t += TPB) {
        int r = t / 160, c = t % 160;
        float acc = bD2[c];
        for (int i = 0; i < 25; i++) acc = fmaf(cfs[r][i], D2[i * 160 + c], acc);
        int g = r * 20 + c / 8, c8 = c % 8;
        if (c8 < 3) dec2s[g][c8] = acc;
        else cf2s[g][c8 - 3] = fmaxf(acc, 0.0f);
    }
    __syncthreads();

    // ---- decoder stage 3 + compose output ----
    float* outb = out + (size_t)b * (NPTS * 3);
    for (int t = tid; t < NPTS * 3; t += TPB) {
        int n = t / 3, c = t % 3;
        int g = n / 20;
        int m = n / 400;
        int r60 = (n % 20) * 3 + c;
        float acc = bD3[r60];
        for (int i = 0; i < 5; i++) acc = fmaf(cf2s[g][i], D3[i * 60 + r60], acc);
        // out = ((dec*R3 + dec2)*R2 + dec3)*R1, R2 = 1
        float val = ((decv[m][c] * 2.0f + dec2s[g][c]) + acc) * 0.3f;
        outb[t] = val;
    }
}

extern "C" void kernel_launch(void* const* d_in, const int* in_sizes, int n_in,
                              void* d_out, int out_size, void* d_ws, size_t ws_size,
                              hipStream_t stream) {
    const float* P   = (const float*)d_in[0];
    const float* W1  = (const float*)d_in[1];
    const float* b1  = (const float*)d_in[2];
    const float* W2  = (const float*)d_in[3];
    const float* b2  = (const float*)d_in[4];
    const float* W3  = (const float*)d_in[5];
    const float* b3  = (const float*)d_in[6];
    const float* D1  = (const float*)d_in[7];
    const float* bD1 = (const float*)d_in[8];
    const float* D2  = (const float*)d_in[9];
    const float* bD2 = (const float*)d_in[10];
    const float* D3  = (const float*)d_in[11];
    const float* bD3 = (const float*)d_in[12];
    float* out = (float*)d_out;

    int B = in_sizes[0] / (NPTS * 3);
    hipLaunchKernelGGL(fused_kernel, dim3(B), dim3(TPB), 0, stream,
                       P, W1, b1, W2, b2, W3, b3, D1, bD1, D2, bD2, D3, bD3, out);
}

// Round 10
// 184.254 us; speedup vs baseline: 1.4638x; 1.0106x over previous
//
#include <hip/hip_runtime.h>

#define TPB 512
#define NW 8
#define NPTS 2000
#define M1C 100
#define M2C 5
#define KNN 20
#define CANDCAP 128

typedef float v2f __attribute__((ext_vector_type(2)));

// Bitwise-exact squared distance matching numpy fp32 sequential sum:
// ((dx*dx + dy*dy) + dz*dz), no FMA contraction.
__device__ __forceinline__ float dist3(float px, float py, float pz,
                                       float qx, float qy, float qz) {
#pragma clang fp contract(off)
    float dx = px - qx, dy = py - qy, dz = pz - qz;
    return dx * dx + dy * dy + dz * dz;
}

// Packed pair variant: identical per-component op order (sub,mul,add,add),
// so each component is bitwise identical to dist3.
__device__ __forceinline__ v2f dist3p(v2f px, v2f py, v2f pz, v2f q0, v2f q1, v2f q2) {
#pragma clang fp contract(off)
    v2f dx = px - q0, dy = py - q1, dz = pz - q2;
    v2f ax = dx * dx;
    v2f ay = dy * dy;
    v2f az = dz * dz;
    return (ax + ay) + az;
}

// Fused wave64 (value,index) argmax, min-index tie-break, DPP chain.
// (kept for FPS2; FPS1 uses the cheaper split max+ballot below)
#define ARGMAX_STEP(ctrl, rm)                                                        \
    do {                                                                             \
        float ov = __int_as_float(__builtin_amdgcn_update_dpp(                       \
            (int)0xff800000, __float_as_int(v), ctrl, rm, 0xf, false));              \
        int oi = __builtin_amdgcn_update_dpp(0x7fffffff, i, ctrl, rm, 0xf, false);   \
        bool take = (ov > v) || (ov == v && oi < i);                                 \
        v = take ? ov : v;                                                           \
        i = take ? oi : i;                                                           \
    } while (0)

__device__ __forceinline__ void wave_argmax(float& v, int& i) {
    ARGMAX_STEP(0x111, 0xf);
    ARGMAX_STEP(0x112, 0xf);
    ARGMAX_STEP(0x114, 0xf);
    ARGMAX_STEP(0x118, 0xf);
    ARGMAX_STEP(0x142, 0xa);
    ARGMAX_STEP(0x143, 0xc);
    v = __int_as_float(__builtin_amdgcn_readlane(__float_as_int(v), 63));
    i = __builtin_amdgcn_readlane(i, 63);
}

#define FMAX_STEP(ctrl, rm)                                                          \
    do {                                                                             \
        float _t = __int_as_float(__builtin_amdgcn_update_dpp(                       \
            (int)0xff800000, __float_as_int(x), ctrl, rm, 0xf, false));              \
        x = fmaxf(x, _t);                                                            \
    } while (0)

__device__ __forceinline__ float wave_fmax(float x) {
    FMAX_STEP(0x111, 0xf);
    FMAX_STEP(0x112, 0xf);
    FMAX_STEP(0x114, 0xf);
    FMAX_STEP(0x118, 0xf);
    FMAX_STEP(0x142, 0xa);
    FMAX_STEP(0x143, 0xc);
    return __int_as_float(__builtin_amdgcn_readlane(__float_as_int(x), 63));
}

// int-min DPP chain (same lane pattern as FMAX, identity INT_MAX) — slow
// path of the split argmax, exact min-index over matched lanes.
#define IMIN_STEP(var, ctrl, rm)                                                     \
    do {                                                                             \
        int _t = __builtin_amdgcn_update_dpp(0x7fffffff, var, ctrl, rm, 0xf, false); \
        var = (_t < var) ? _t : var;                                                 \
    } while (0)

__device__ __forceinline__ int wave_imin(int c) {
    IMIN_STEP(c, 0x111, 0xf);
    IMIN_STEP(c, 0x112, 0xf);
    IMIN_STEP(c, 0x114, 0xf);
    IMIN_STEP(c, 0x118, 0xf);
    IMIN_STEP(c, 0x142, 0xa);
    IMIN_STEP(c, 0x143, 0xc);
    return __builtin_amdgcn_readlane(c, 63);
}

// ============ Fused kernel ============
// R21 = R19 (114.5us) + SELF-CONTAINED candidate slots: the polled word IS
// the payload. R19's serial chain ended poll -> THEN read sA/sZ (another
// ~120-240 cyc LDS round trip). Now each wave's candidate (gv, gbi) packs
// into one b64 {f32 gv, u32 ((it+1)<<12)|gbi} released by lane 0; pollers
// read the four 8B slots and on tag-match the combine inputs are already in
// registers -- zero post-poll reads, no acquire fence (payload is the
// atomic itself). Next-q = one uniform sp[win] b128 broadcast (same staged
// bits as the old winner-lane register path; replaces the cndmask blob).
// Combine semantics unchanged: (max value, min index) on identical bits.
__global__ __launch_bounds__(TPB, 2) void fused_kernel(
    const float* __restrict__ P,
    const float* __restrict__ W1, const float* __restrict__ b1,
    const float* __restrict__ W2, const float* __restrict__ b2,
    const float* __restrict__ W3, const float* __restrict__ b3,
    const float* __restrict__ D1, const float* __restrict__ bD1,
    const float* __restrict__ D2, const float* __restrict__ bD2,
    const float* __restrict__ D3, const float* __restrict__ bD3,
    float* __restrict__ out)
{
    __shared__ __align__(16) float4 sp[NPTS];   // packed (x,y,z,0)
    __shared__ float smpx[M1C], smpy[M1C], smpz[M1C];
    __shared__ float s2x[M2C], s2y[M2C], s2z[M2C];
    __shared__ float f1s[M1C][5];
    __shared__ float knd[NW][CANDCAP];
    __shared__ int   kni[NW][CANDCAP];
    __shared__ float vin[M2C][KNN][8];
    __shared__ __align__(16) unsigned long long cnd[2][4];  // {f32 val, u32 tag}
    __shared__ int prog;                      // highest published FPS1 sample
    __shared__ float f2s[M2C][25];
    __shared__ float latent[45];
    __shared__ float decv[M2C][3];
    __shared__ float cfs[M2C][25];
    __shared__ float dec2s[M1C][3];
    __shared__ float cf2s[M1C][5];
    __shared__ float w2s[200], b2s[25], w3s[1260], b3s[45];

    const int b = blockIdx.x;
    const int tid = threadIdx.x;
    const int lane = tid & 63;
    const int wid = tid >> 6;

    const float R1SQ = (float)(0.3 * 0.3);   // f64 product then cast
    const float R2SQ = 1.0f;
    const float INVR1 = 1.0f / 0.3f;

    // ---- staging (all 8 waves) ----
    const float* Pb = P + (size_t)b * (NPTS * 3);
    for (int j = tid; j < NPTS; j += TPB) {
        sp[j] = make_float4(Pb[3 * j + 0], Pb[3 * j + 1], Pb[3 * j + 2], 0.0f);
    }
    for (int t = tid; t < 200; t += TPB) w2s[t] = W2[t];
    for (int t = tid; t < 25; t += TPB) b2s[t] = b2[t];
    for (int t = tid; t < 1260; t += TPB) w3s[t] = W3[t];
    for (int t = tid; t < 45; t += TPB) b3s[t] = b3[t];
    if (tid < 8) ((unsigned long long*)cnd)[tid] = 0ull;   // tags = 0
    if (tid == 0) prog = -1;
    __syncthreads();

    if (wid < 4) {
        // ================= producers: FPS1 (waves 0-3, tid 0..255) =================
        __builtin_amdgcn_s_setprio(1);
        v2f px2[4], py2[4], pz2[4], mind2[4];
#pragma unroll
        for (int p = 0; p < 4; ++p) {
#pragma unroll
            for (int h = 0; h < 2; ++h) {
                int k = 2 * p + h;
                int j = tid + (k << 8);
                bool v = j < NPTS;
                float4 A = sp[v ? j : 0];
                px2[p][h] = v ? A.x : 1e18f;
                py2[p][h] = v ? A.y : 1e18f;
                pz2[p][h] = v ? A.z : 1e18f;
                mind2[p][h] = v ? 1e10f : -1.0f;
            }
        }

        float4 qq0 = sp[0];
        float qx = qq0.x, qy = qq0.y, qz = qq0.z;
        for (int it = 0; it < M1C; ++it) {
            if (tid == 0) {
                smpx[it] = qx; smpy[it] = qy; smpz[it] = qz;
                __hip_atomic_store(&prog, it, __ATOMIC_RELEASE,
                                   __HIP_MEMORY_SCOPE_WORKGROUP);
            }
            if (it == M1C - 1) break;

            v2f q0 = {qx, qx}, q1 = {qy, qy}, q2 = {qz, qz};
            float m[8];
#pragma unroll
            for (int p = 0; p < 4; ++p) {
                v2f d = dist3p(px2[p], py2[p], pz2[p], q0, q1, q2);
                v2f mm;
                mm[0] = fminf(mind2[p][0], d[0]);
                mm[1] = fminf(mind2[p][1], d[1]);
                mind2[p] = mm;
                m[2 * p] = mm[0];
                m[2 * p + 1] = mm[1];
            }
            // tree argmax over 8 chunks; strict > keeps lowest chunk on ties
            float va = m[0]; int ka = 0; if (m[1] > va) { va = m[1]; ka = 1; }
            float vb = m[2]; int kb = 2; if (m[3] > vb) { vb = m[3]; kb = 3; }
            float vc = m[4]; int kc = 4; if (m[5] > vc) { vc = m[5]; kc = 5; }
            float vd = m[6]; int kd = 6; if (m[7] > vd) { vd = m[7]; kd = 7; }
            if (vb > va) { va = vb; ka = kb; }
            if (vd > vc) { vc = vd; kc = kd; }
            if (vc > va) { va = vc; ka = kc; }
            float lv = va;                      // lane-local best value
            int   li = tid + (ka << 8);         // lane-local best index
            // ---- split wave argmax: cheap value max + ballot index ----
            float gv = wave_fmax(lv);           // 2-op/step DPP chain
            unsigned long long mk = __ballot(lv == gv);   // >=1 lane matches
            int gbi;
            if (__popcll(mk) == 1) {            // uniform branch, ~always
                gbi = __builtin_amdgcn_readlane(li, (int)__builtin_ctzll(mk));
            } else {                            // exact min-index tie-break
                int c = (lv == gv) ? li : 0x7fffffff;
                gbi = wave_imin(c);
            }
            int p = it & 1;
            // publish self-contained candidate: {f32 gv, u32 tag<<12|idx}
            if (lane == 0) {
                unsigned long long pk =
                    ((unsigned long long)(unsigned)(((it + 1) << 12) | gbi) << 32) |
                    (unsigned long long)(unsigned)__float_as_int(gv);
                __hip_atomic_store(&cnd[p][wid], pk, __ATOMIC_RELEASE,
                                   __HIP_MEMORY_SCOPE_WORKGROUP);
            }
            // hot spin: payload IS the flag (tag == it+1 on all 4 slots)
            unsigned long long c0, c1, c2, c3;
            {
                const unsigned need = (unsigned)(it + 1);
                for (;;) {
                    c0 = __hip_atomic_load(&cnd[p][0], __ATOMIC_RELAXED,
                                           __HIP_MEMORY_SCOPE_WORKGROUP);
                    c1 = __hip_atomic_load(&cnd[p][1], __ATOMIC_RELAXED,
                                           __HIP_MEMORY_SCOPE_WORKGROUP);
                    c2 = __hip_atomic_load(&cnd[p][2], __ATOMIC_RELAXED,
                                           __HIP_MEMORY_SCOPE_WORKGROUP);
                    c3 = __hip_atomic_load(&cnd[p][3], __ATOMIC_RELAXED,
                                           __HIP_MEMORY_SCOPE_WORKGROUP);
                    if (((unsigned)(c0 >> 32) >> 12) == need &&
                        ((unsigned)(c1 >> 32) >> 12) == need &&
                        ((unsigned)(c2 >> 32) >> 12) == need &&
                        ((unsigned)(c3 >> 32) >> 12) == need) break;
                }
                // no acquire fence needed: combine consumes only the atomic
                // payloads themselves; sp[] is constant after staging barrier.
            }
            // combine in registers, same comparison tree, min-index ties
            float cva = __int_as_float((int)(unsigned)c0);
            int   cia = (int)((unsigned)(c0 >> 32) & 0xfffu);
            {
                float v1 = __int_as_float((int)(unsigned)c1);
                int   i1 = (int)((unsigned)(c1 >> 32) & 0xfffu);
                bool t = (v1 > cva) || (v1 == cva && i1 < cia);
                if (t) { cva = v1; cia = i1; }
            }
            float cvb = __int_as_float((int)(unsigned)c2);
            int   cib = (int)((unsigned)(c2 >> 32) & 0xfffu);
            {
                float v3 = __int_as_float((int)(unsigned)c3);
                int   i3 = (int)((unsigned)(c3 >> 32) & 0xfffu);
                bool t = (v3 > cvb) || (v3 == cvb && i3 < cib);
                if (t) { cvb = v3; cib = i3; }
            }
            bool t = (cvb > cva) || (cvb == cva && cib < cia);
            int win = t ? cib : cia;
            float4 qq = sp[win];               // uniform addr -> one b128 broadcast
            qx = qq.x; qy = qq.y; qz = qq.z;
        }

        if (wid == 0) {
            // ---- FPS2: 5 from 100 (single wave, in-LDS smp) ----
            float ax = smpx[lane], ay = smpy[lane], az = smpz[lane];
            bool vb2 = lane < (M1C - 64);
            float bx2 = vb2 ? smpx[lane + 64] : 1e18f;
            float by2 = vb2 ? smpy[lane + 64] : 1e18f;
            float bz2 = vb2 ? smpz[lane + 64] : 1e18f;
            float m2a = 1e10f;
            float m2b = vb2 ? 1e10f : -1.0f;
            int last2 = 0;
            for (int it = 0; it < M2C; ++it) {
                float fx = smpx[last2], fy = smpy[last2], fz = smpz[last2];
                if (lane == 0) { s2x[it] = fx; s2y[it] = fy; s2z[it] = fz; }
                m2a = fminf(m2a, dist3(ax, ay, az, fx, fy, fz));
                m2b = fminf(m2b, dist3(bx2, by2, bz2, fx, fy, fz));
                float v = m2a; int i = lane;
                if (m2b > v) { v = m2b; i = lane + 64; }
                wave_argmax(v, i);
                last2 = i;
            }
        }
        __builtin_amdgcn_s_setprio(0);
    } else {
        // ================= consumers: knn1 + MLP1 (waves 4-7) =================
        float rw1[15], rb1[5];
#pragma unroll
        for (int i = 0; i < 15; ++i) rw1[i] = W1[i];
#pragma unroll
        for (int i = 0; i < 5; ++i) rb1[i] = b1[i];

        for (int s = wid - 4; s < M1C; s += 4) {
            // wait until producer published sample s
            while (__hip_atomic_load(&prog, __ATOMIC_ACQUIRE,
                                     __HIP_MEMORY_SCOPE_WORKGROUP) < s)
                __builtin_amdgcn_s_sleep(1);
            float qx = smpx[s], qy = smpy[s], qz = smpz[s];
            int cn = 0;
#pragma unroll 4
            for (int c = 0; c < 32; ++c) {
                int j = c * 64 + lane;
                float d = 0.0f; bool pred = false;
                if (j < NPTS) {
                    float4 pj = sp[j];
                    d = dist3(pj.x, pj.y, pj.z, qx, qy, qz);
                    pred = (d <= R1SQ);
                }
                unsigned long long mb = __ballot(pred);
                if (pred) {
                    int pos = cn + (int)__popcll(mb & ((1ull << lane) - 1ull));
                    if (pos < CANDCAP) { knd[wid][pos] = d; kni[wid][pos] = j; }
                }
                cn += (int)__popcll(mb);
            }
            if (cn > CANDCAP) cn = CANDCAP;  // P(Poisson λ≈14 > 128) ~ 1e-68
            float fmx[5];
#pragma unroll
            for (int f = 0; f < 5; ++f) fmx[f] = -1e30f;
            for (int t = lane; t < cn; t += 64) {
                float d = knd[wid][t]; int j = kni[wid][t];
                bool valid = true;
                if (cn > KNN) {
                    int rank = 0;
                    for (int u = 0; u < cn; ++u) {
                        float du = knd[wid][u]; int iu = kni[wid][u];
                        rank += (du < d || (du == d && iu < j)) ? 1 : 0;
                    }
                    valid = rank < KNN;   // replicates top_k stability (ties -> lower idx)
                }
                if (valid) {
                    float4 pj = sp[j];
                    float rx = (pj.x - qx) * INVR1;
                    float ry = (pj.y - qy) * INVR1;
                    float rz = (pj.z - qz) * INVR1;
#pragma unroll
                    for (int f = 0; f < 5; ++f) {
                        float h = fmaf(rx, rw1[f], fmaf(ry, rw1[5 + f], fmaf(rz, rw1[10 + f], rb1[f])));
                        fmx[f] = fmaxf(fmx[f], fmaxf(h, 0.0f));
                    }
                }
            }
#pragma unroll
            for (int f = 0; f < 5; ++f) fmx[f] = wave_fmax(fmx[f]);
            if (lane == 0) {
#pragma unroll
                for (int f = 0; f < 5; ++f) f1s[s][f] = fmx[f];
            }
        }
    }
    __syncthreads();   // all 8 waves reach exactly once

    // ================= tail: knn2 + MLP2 (DPP-free), MLP3, decoder =================
    for (int s = wid; s < M2C; s += NW) {
        float qx2 = s2x[s], qy2 = s2y[s], qz2 = s2z[s];
        int cn = 0;
#pragma unroll
        for (int c = 0; c < 2; ++c) {
            int j = c * 64 + lane;
            float d = 0.0f; bool pred = false;
            if (j < M1C) {
                d = dist3(smpx[j], smpy[j], smpz[j], qx2, qy2, qz2);
                pred = (d <= R2SQ);
            }
            unsigned long long mb = __ballot(pred);
            if (pred) {
                int pos = cn + (int)__popcll(mb & ((1ull << lane) - 1ull));
                knd[wid][pos] = d; kni[wid][pos] = j;   // cn<=100<CANDCAP
            }
            cn += (int)__popcll(mb);
        }
        // build valid-candidate input vectors (order-independent for max)
        int nv = 0;
#pragma unroll
        for (int c = 0; c < 2; ++c) {
            int t = c * 64 + lane;
            bool valid = false;
            float in8[8];
            if (t < cn) {
                float d = knd[wid][t]; int j = kni[wid][t];
                valid = true;
                if (cn > KNN) {
                    int rank = 0;
                    for (int u = 0; u < cn; ++u) {
                        float du = knd[wid][u]; int iu = kni[wid][u];
                        rank += (du < d || (du == d && iu < j)) ? 1 : 0;
                    }
                    valid = rank < KNN;
                }
                if (valid) {
                    in8[0] = smpx[j] - qx2; in8[1] = smpy[j] - qy2; in8[2] = smpz[j] - qz2;
#pragma unroll
                    for (int f = 0; f < 5; ++f) in8[3 + f] = f1s[j][f];
                }
            }
            unsigned long long mb = __ballot(valid);
            if (valid) {
                int pos = nv + (int)__popcll(mb & ((1ull << lane) - 1ull));
#pragma unroll
                for (int i = 0; i < 8; ++i) vin[s][pos][i] = in8[i];   // nv<=20
            }
            nv += (int)__popcll(mb);
        }
        // feature-per-lane max (no DPP chains); nv >= 1 (sample in own ball)
        if (lane < 25) {
            float hmx = -1e30f;
            for (int c = 0; c < nv; ++c) {
                float h = b2s[lane];
#pragma unroll
                for (int i = 0; i < 8; ++i) h = fmaf(vin[s][c][i], w2s[i * 25 + lane], h);
                hmx = fmaxf(hmx, fmaxf(h, 0.0f));
            }
            f2s[s][lane] = hmx;
        }
    }
    __syncthreads();

    // ---- MLP3 + max-pool -> latent (45) ----
    if (wid == 0 && lane < 45) {
        float lm = -1e30f;
        for (int r = 0; r < M2C; ++r) {
            float h = b3s[lane];
            h = fmaf(s2x[r] * 0.5f, w3s[0 * 45 + lane], h);
            h = fmaf(s2y[r] * 0.5f, w3s[1 * 45 + lane], h);
            h = fmaf(s2z[r] * 0.5f, w3s[2 * 45 + lane], h);
#pragma unroll
            for (int i = 0; i < 25; ++i) h = fmaf(f2s[r][i], w3s[(3 + i) * 45 + lane], h);
            lm = fmaxf(lm, fmaxf(h, 0.0f));
        }
        latent[lane] = lm;
    }
    __syncthreads();

    // ---- decoder stage 1: latent @ D1 + bD1 -> (5, 28) ----
    for (int t = tid; t < 140; t += TPB) {
        float acc = bD1[t];
        for (int i = 0; i < 45; i++) acc = fmaf(latent[i], D1[i * 140 + t], acc);
        int r = t / 28, c = t % 28;
        if (c < 3) decv[r][c] = acc;
        else cfs[r][c - 3] = fmaxf(acc, 0.0f);
    }
    __syncthreads();

    // ---- decoder stage 2: cf @ D2 + bD2 -> (100, 8) ----
    for (int t = tid; t < 800; t += TPB) {
        int r = t / 160, c = t % 160;
        float acc = bD2[c];
        for (int i = 0; i < 25; i++) acc = fmaf(cfs[r][i], D2[i * 160 + c], acc);
        int g = r * 20 + c / 8, c8 = c % 8;
        if (c8 < 3) dec2s[g][c8] = acc;
        else cf2s[g][c8 - 3] = fmaxf(acc, 0.0f);
    }
    __syncthreads();

    // ---- decoder stage 3 + compose output ----
    float* outb = out + (size_t)b * (NPTS * 3);
    for (int t = tid; t < NPTS * 3; t += TPB) {
        int n = t / 3, c = t % 3;
        int g = n / 20;
        int m = n / 400;
        int r60 = (n % 20) * 3 + c;
        float acc = bD3[r60];
        for (int i = 0; i < 5; i++) acc = fmaf(cf2s[g][i], D3[i * 60 + r60], acc);
        // out = ((dec*R3 + dec2)*R2 + dec3)*R1, R2 = 1
        float val = ((decv[m][c] * 2.0f + dec2s[g][c]) + acc) * 0.3f;
        outb[t] = val;
    }
}

extern "C" void kernel_launch(void* const* d_in, const int* in_sizes, int n_in,
                              void* d_out, int out_size, void* d_ws, size_t ws_size,
                              hipStream_t stream) {
    const float* P   = (const float*)d_in[0];
    const float* W1  = (const float*)d_in[1];
    const float* b1  = (const float*)d_in[2];
    const float* W2  = (const float*)d_in[3];
    const float* b2  = (const float*)d_in[4];
    const float* W3  = (const float*)d_in[5];
    const float* b3  = (const float*)d_in[6];
    const float* D1  = (const float*)d_in[7];
    const float* bD1 = (const float*)d_in[8];
    const float* D2  = (const float*)d_in[9];
    const float* bD2 = (const float*)d_in[10];
    const float* D3  = (const float*)d_in[11];
    const float* bD3 = (const float*)d_in[12];
    float* out = (float*)d_out;

    int B = in_sizes[0] / (NPTS * 3);
    hipLaunchKernelGGL(fused_kernel, dim3(B), dim3(TPB), 0, stream,
                       P, W1, b1, W2, b2, W3, b3, D1, bD1, D2, bD2, D3, bD3, out);
}